// Round 1
// baseline (4187.700 us; speedup 1.0000x reference)
//
#include <hip/hip_runtime.h>
#include <hip/hip_bf16.h>
#include <math.h>

#define S_LEN 2048
#define D_DIM 1024
#define B_BATCH 8
#define R_ROWS (B_BATCH * S_LEN)   // 16384
#define BD_ROWS (B_BATCH * D_DIM)  // 8192

__device__ __forceinline__ float gelu_exact(float x) {
    return 0.5f * x * (1.0f + erff(x * 0.70710678118654752f));
}

// ---------------------------------------------------------------- embedding
__global__ __launch_bounds__(256) void emb_kernel(
    const int* __restrict__ x, const float* __restrict__ tok,
    const float* __restrict__ pos, float* __restrict__ out)
{
    const int row = blockIdx.x;            // b*S + s
    const int tid = threadIdx.x;
    const int t = x[row];
    const int s = row & (S_LEN - 1);
    const float4* tp = (const float4*)(tok + (size_t)t * D_DIM);
    const float4* pp = (const float4*)(pos + (size_t)s * D_DIM);
    float4* op = (float4*)(out + (size_t)row * D_DIM);
    float4 a = tp[tid], b = pp[tid];
    op[tid] = make_float4(a.x + b.x, a.y + b.y, a.z + b.z, a.w + b.w);
}

// -------------------------------------------------- conv-as-GEMM (and GEMM)
// out[r,o] = act(bias[o] + sum_tap sum_i A[rowShift(r,tap), i] * W[tap,i,o])
__global__ __launch_bounds__(256) void gemm_conv(
    const float* __restrict__ A, const float* __restrict__ W,
    const float* __restrict__ bias, float* __restrict__ out,
    int ntaps, int doGelu)
{
    __shared__ float As[16][128];
    __shared__ float Bs[16][128];
    const int tid = threadIdx.x;
    const int tx = tid & 15, ty = tid >> 4;
    const int row0 = blockIdx.x * 128;
    const int col0 = blockIdx.y * 128;
    const int lr = tid >> 1;
    const int lc = (tid & 1) * 8;
    const int br = tid >> 4;
    const int bc = (tid & 15) * 8;
    const int halo = ntaps >> 1;

    float acc[8][8];
#pragma unroll
    for (int i = 0; i < 8; i++)
#pragma unroll
        for (int j = 0; j < 8; j++) acc[i][j] = 0.0f;

    for (int tap = 0; tap < ntaps; ++tap) {
        const int gr = row0 + lr;
        const int s  = gr & (S_LEN - 1);
        const int bb = gr >> 11;
        const int ss = s + tap - halo;
        const bool valid = (ss >= 0) && (ss < S_LEN);
        const float* arow = A + ((size_t)(bb * S_LEN + ss)) * D_DIM;
        const float* Wt = W + (size_t)tap * D_DIM * D_DIM;
        for (int k0 = 0; k0 < D_DIM; k0 += 16) {
            float4 a0 = make_float4(0.f, 0.f, 0.f, 0.f), a1 = a0;
            if (valid) {
                a0 = *(const float4*)(arow + k0 + lc);
                a1 = *(const float4*)(arow + k0 + lc + 4);
            }
            As[lc + 0][lr] = a0.x; As[lc + 1][lr] = a0.y;
            As[lc + 2][lr] = a0.z; As[lc + 3][lr] = a0.w;
            As[lc + 4][lr] = a1.x; As[lc + 5][lr] = a1.y;
            As[lc + 6][lr] = a1.z; As[lc + 7][lr] = a1.w;
            const float* wrow = Wt + (size_t)(k0 + br) * D_DIM + col0 + bc;
            *(float4*)&Bs[br][bc]     = *(const float4*)(wrow);
            *(float4*)&Bs[br][bc + 4] = *(const float4*)(wrow + 4);
            __syncthreads();
#pragma unroll
            for (int kk = 0; kk < 16; ++kk) {
                float a[8], b[8];
                *(float4*)&a[0] = *(const float4*)&As[kk][ty * 8];
                *(float4*)&a[4] = *(const float4*)&As[kk][ty * 8 + 4];
                *(float4*)&b[0] = *(const float4*)&Bs[kk][tx * 8];
                *(float4*)&b[4] = *(const float4*)&Bs[kk][tx * 8 + 4];
#pragma unroll
                for (int i = 0; i < 8; i++)
#pragma unroll
                    for (int j = 0; j < 8; j++)
                        acc[i][j] = fmaf(a[i], b[j], acc[i][j]);
            }
            __syncthreads();
        }
    }
    float bv[8];
    *(float4*)&bv[0] = *(const float4*)(bias + col0 + tx * 8);
    *(float4*)&bv[4] = *(const float4*)(bias + col0 + tx * 8 + 4);
#pragma unroll
    for (int i = 0; i < 8; i++) {
        const int gr = row0 + ty * 8 + i;
        float v[8];
#pragma unroll
        for (int j = 0; j < 8; j++) {
            float t = acc[i][j] + bv[j];
            v[j] = doGelu ? gelu_exact(t) : t;
        }
        float* orow = out + (size_t)gr * D_DIM + col0 + tx * 8;
        *(float4*)(orow)     = *(float4*)&v[0];
        *(float4*)(orow + 4) = *(float4*)&v[4];
    }
}

// ---------------------------------------------------------------- layernorm
__global__ __launch_bounds__(256) void ln_kernel(
    const float* __restrict__ in, const float* __restrict__ g,
    const float* __restrict__ beta, float* __restrict__ out,
    float* __restrict__ out2)
{
    const int row = blockIdx.x;
    const int tid = threadIdx.x;
    float4 v = ((const float4*)(in + (size_t)row * D_DIM))[tid];
    float s  = v.x + v.y + v.z + v.w;
    float s2 = v.x * v.x + v.y * v.y + v.z * v.z + v.w * v.w;
#pragma unroll
    for (int off = 32; off > 0; off >>= 1) {
        s  += __shfl_xor(s, off);
        s2 += __shfl_xor(s2, off);
    }
    __shared__ float red[8];
    if ((tid & 63) == 0) { red[(tid >> 6) * 2] = s; red[(tid >> 6) * 2 + 1] = s2; }
    __syncthreads();
    s  = red[0] + red[2] + red[4] + red[6];
    s2 = red[1] + red[3] + red[5] + red[7];
    const float m   = s * (1.0f / D_DIM);
    const float var = s2 * (1.0f / D_DIM) - m * m;
    const float rs  = rsqrtf(var + 1e-5f);
    float4 gg = ((const float4*)g)[tid];
    float4 bb = ((const float4*)beta)[tid];
    float4 o;
    o.x = (v.x - m) * rs * gg.x + bb.x;
    o.y = (v.y - m) * rs * gg.y + bb.y;
    o.z = (v.z - m) * rs * gg.z + bb.z;
    o.w = (v.w - m) * rs * gg.w + bb.w;
    ((float4*)(out + (size_t)row * D_DIM))[tid] = o;
    if (out2) ((float4*)(out2 + (size_t)row * D_DIM))[tid] = o;
}

// -------------------------------------------------- batched 2D transpose
// in [B][M][N] -> out [B][N][M]
__global__ __launch_bounds__(256) void transposeMN(
    const float* __restrict__ in, float* __restrict__ out, int M, int N)
{
    __shared__ float t[32][33];
    const int b = blockIdx.z;
    const int n0 = blockIdx.x * 32, m0 = blockIdx.y * 32;
    const int tx = threadIdx.x, ty = threadIdx.y;
    const float* ip = in + (size_t)b * M * N;
    float* op = out + (size_t)b * M * N;
#pragma unroll
    for (int u = 0; u < 4; u++)
        t[ty + u * 8][tx] = ip[(size_t)(m0 + ty + u * 8) * N + n0 + tx];
    __syncthreads();
#pragma unroll
    for (int u = 0; u < 4; u++)
        op[(size_t)(n0 + ty + u * 8) * M + m0 + tx] = t[tx][ty + u * 8];
}

// ------------------------------------------------------------- forward FFT
// one workgroup per (b,d) row of [B,D,S]; 2048-pt radix-2; also accumulates
// count(mag^2 > 0.01*max_mag^2) into counts[b]
__global__ __launch_bounds__(256) void fft_fwd(
    const float* __restrict__ in, float2* __restrict__ X, int* __restrict__ counts)
{
    __shared__ float re[2048], im[2048], twr[1024], twi[1024];
    __shared__ float redf[4];
    __shared__ int   redi[4];
    const int tid = threadIdx.x;
    const int row = blockIdx.x;          // b*D + d
    const float* src = in + (size_t)row * S_LEN;
#pragma unroll
    for (int u = 0; u < 4; u++) {
        int j = tid + u * 256;
        float ang = -3.14159265358979f * (float)j * (1.0f / 1024.0f);
        float sn, cs; __sincosf(ang, &sn, &cs);
        twr[j] = cs; twi[j] = sn;
    }
#pragma unroll
    for (int u = 0; u < 8; u++) {
        int i = tid + u * 256;
        float v = src[i];
        int r = __brev((unsigned)i) >> 21;
        re[r] = v; im[r] = 0.0f;
    }
    __syncthreads();
    for (int st = 1; st <= 11; ++st) {
        const int mh = 1 << (st - 1);
#pragma unroll
        for (int u = 0; u < 4; u++) {
            int tb = tid + u * 256;
            int gidx = tb >> (st - 1);
            int j = tb & (mh - 1);
            int i1 = (gidx << st) + j;
            int i2 = i1 + mh;
            int ti = j << (11 - st);
            float wr = twr[ti], wi = twi[ti];
            float xr = re[i2], xi = im[i2];
            float vr = xr * wr - xi * wi;
            float vi = xr * wi + xi * wr;
            float ur = re[i1], ui = im[i1];
            re[i1] = ur + vr; im[i1] = ui + vi;
            re[i2] = ur - vr; im[i2] = ui - vi;
        }
        __syncthreads();
    }
    float2* dst = X + (size_t)row * S_LEN;
    float lmax = 0.0f;
#pragma unroll
    for (int u = 0; u < 8; u++) {
        int k = tid + u * 256;
        float xr = re[k], xi = im[k];
        dst[k] = make_float2(xr, xi);
        lmax = fmaxf(lmax, xr * xr + xi * xi);
    }
#pragma unroll
    for (int off = 32; off > 0; off >>= 1) lmax = fmaxf(lmax, __shfl_xor(lmax, off));
    if ((tid & 63) == 0) redf[tid >> 6] = lmax;
    __syncthreads();
    const float bmax = fmaxf(fmaxf(redf[0], redf[1]), fmaxf(redf[2], redf[3]));
    const float thr = 0.01f * bmax;
    int lc = 0;
#pragma unroll
    for (int u = 0; u < 8; u++) {
        int k = tid + u * 256;
        float xr = re[k], xi = im[k];
        lc += ((xr * xr + xi * xi) > thr) ? 1 : 0;
    }
#pragma unroll
    for (int off = 32; off > 0; off >>= 1) lc += __shfl_xor(lc, off);
    __syncthreads();
    if ((tid & 63) == 0) redi[tid >> 6] = lc;
    __syncthreads();
    if (tid == 0)
        atomicAdd(&counts[row >> 10], redi[0] + redi[1] + redi[2] + redi[3]);
}

// ------------------------------------------------------------- N from counts
__global__ void calc_n(const int* __restrict__ counts, int* __restrict__ Ndev)
{
    if (threadIdx.x == 0 && blockIdx.x == 0) {
        for (int b = 0; b < B_BATCH; b++) {
            float c = (float)counts[b] * (1.0f / 2097152.0f);  // /(S*D)
            float cr = 0.5f * (1.0f - c);
            cr = fminf(fmaxf(cr, 0.1f), 1.0f);
            int n = (int)(cr * 2048.0f);   // truncation like astype(int32)
            n = n < 1 ? 1 : (n > S_LEN ? S_LEN : n);
            Ndev[b] = n;
        }
    }
}

// ------------------------------------------------------- masked inverse FFT
__global__ __launch_bounds__(256) void fft_inv(
    const float2* __restrict__ X, const int* __restrict__ Ndev,
    float* __restrict__ out)
{
    __shared__ float re[2048], im[2048], twr[1024], twi[1024];
    const int tid = threadIdx.x;
    const int row = blockIdx.x;          // b*D + d
    const int Nb = Ndev[row >> 10];
    const float2* src = X + (size_t)row * S_LEN;
#pragma unroll
    for (int u = 0; u < 4; u++) {
        int j = tid + u * 256;
        float ang = 3.14159265358979f * (float)j * (1.0f / 1024.0f);
        float sn, cs; __sincosf(ang, &sn, &cs);
        twr[j] = cs; twi[j] = sn;
    }
#pragma unroll
    for (int u = 0; u < 8; u++) {
        int k = tid + u * 256;
        float2 v = (k < Nb) ? src[k] : make_float2(0.f, 0.f);
        int r = __brev((unsigned)k) >> 21;
        re[r] = v.x; im[r] = v.y;
    }
    __syncthreads();
    for (int st = 1; st <= 11; ++st) {
        const int mh = 1 << (st - 1);
#pragma unroll
        for (int u = 0; u < 4; u++) {
            int tb = tid + u * 256;
            int gidx = tb >> (st - 1);
            int j = tb & (mh - 1);
            int i1 = (gidx << st) + j;
            int i2 = i1 + mh;
            int ti = j << (11 - st);
            float wr = twr[ti], wi = twi[ti];
            float xr = re[i2], xi = im[i2];
            float vr = xr * wr - xi * wi;
            float vi = xr * wi + xi * wr;
            float ur = re[i1], ui = im[i1];
            re[i1] = ur + vr; im[i1] = ui + vi;
            re[i2] = ur - vr; im[i2] = ui - vi;
        }
        __syncthreads();
    }
    float* dst = out + (size_t)row * S_LEN;
#pragma unroll
    for (int u = 0; u < 8; u++) {
        int k = tid + u * 256;
        dst[k] = re[k] * (1.0f / 2048.0f);   // ifft(...).real
    }
}

// ------------------------------- fused ph-projection row statistics (GEMM)
// px = X@W+b, pt = R@W+b; accumulate per-row sum(px^2), sum(pt^2), sum(px*pt)
__global__ __launch_bounds__(256) void phstats(
    const float* __restrict__ Xin, const float* __restrict__ Rin,
    const float* __restrict__ W, const float* __restrict__ bias,
    float* __restrict__ Sxx, float* __restrict__ Stt, float* __restrict__ Sxt)
{
    __shared__ float AsX[16][128], AsR[16][128], Bs[16][64];
    const int tid = threadIdx.x;
    const int tx = tid & 15, ty = tid >> 4;
    const int row0 = blockIdx.x * 128;
    const int col0 = blockIdx.y * 64;
    const int lr = tid >> 1, lc = (tid & 1) * 8;
    const int wr = tid >> 4, wc = (tid & 15) * 4;
    float accx[8][4], accr[8][4];
#pragma unroll
    for (int i = 0; i < 8; i++)
#pragma unroll
        for (int j = 0; j < 4; j++) { accx[i][j] = 0.f; accr[i][j] = 0.f; }

    for (int k0 = 0; k0 < D_DIM; k0 += 16) {
        const float* xa = Xin + (size_t)(row0 + lr) * D_DIM + k0 + lc;
        const float* ra = Rin + (size_t)(row0 + lr) * D_DIM + k0 + lc;
        float4 x0 = *(const float4*)xa, x1 = *(const float4*)(xa + 4);
        float4 r0 = *(const float4*)ra, r1 = *(const float4*)(ra + 4);
        AsX[lc + 0][lr] = x0.x; AsX[lc + 1][lr] = x0.y; AsX[lc + 2][lr] = x0.z; AsX[lc + 3][lr] = x0.w;
        AsX[lc + 4][lr] = x1.x; AsX[lc + 5][lr] = x1.y; AsX[lc + 6][lr] = x1.z; AsX[lc + 7][lr] = x1.w;
        AsR[lc + 0][lr] = r0.x; AsR[lc + 1][lr] = r0.y; AsR[lc + 2][lr] = r0.z; AsR[lc + 3][lr] = r0.w;
        AsR[lc + 4][lr] = r1.x; AsR[lc + 5][lr] = r1.y; AsR[lc + 6][lr] = r1.z; AsR[lc + 7][lr] = r1.w;
        *(float4*)&Bs[wr][wc] = *(const float4*)(W + (size_t)(k0 + wr) * D_DIM + col0 + wc);
        __syncthreads();
#pragma unroll
        for (int kk = 0; kk < 16; ++kk) {
            float ax[8], ar[8], bv[4];
            *(float4*)&ax[0] = *(const float4*)&AsX[kk][ty * 8];
            *(float4*)&ax[4] = *(const float4*)&AsX[kk][ty * 8 + 4];
            *(float4*)&ar[0] = *(const float4*)&AsR[kk][ty * 8];
            *(float4*)&ar[4] = *(const float4*)&AsR[kk][ty * 8 + 4];
            *(float4*)&bv[0] = *(const float4*)&Bs[kk][tx * 4];
#pragma unroll
            for (int i = 0; i < 8; i++)
#pragma unroll
                for (int j = 0; j < 4; j++) {
                    accx[i][j] = fmaf(ax[i], bv[j], accx[i][j]);
                    accr[i][j] = fmaf(ar[i], bv[j], accr[i][j]);
                }
        }
        __syncthreads();
    }
    float bvals[4];
    *(float4*)bvals = *(const float4*)(bias + col0 + tx * 4);
#pragma unroll
    for (int i = 0; i < 8; i++) {
        const int row = row0 + ty * 8 + i;
        float sxx = 0.f, stt = 0.f, sxt = 0.f;
#pragma unroll
        for (int j = 0; j < 4; j++) {
            float px = accx[i][j] + bvals[j];
            float pt = accr[i][j] + bvals[j];
            sxx = fmaf(px, px, sxx);
            stt = fmaf(pt, pt, stt);
            sxt = fmaf(px, pt, sxt);
        }
#pragma unroll
        for (int off = 1; off < 16; off <<= 1) {
            sxx += __shfl_xor(sxx, off);
            stt += __shfl_xor(stt, off);
            sxt += __shfl_xor(sxt, off);
        }
        if (tx == 0) {
            atomicAdd(&Sxx[row], sxx);
            atomicAdd(&Stt[row], stt);
            atomicAdd(&Sxt[row], sxt);
        }
    }
}

// ------------------------------------------------- per-row loss statistics
__global__ __launch_bounds__(256) void row_stats(
    const float* __restrict__ xifft, const float* __restrict__ recon,
    const float* __restrict__ Sxx, const float* __restrict__ Stt,
    const float* __restrict__ Sxt, const int* __restrict__ Ndev,
    float* __restrict__ gA, float* __restrict__ gB)
{
    const int row = blockIdx.x;    // b*S + s
    const int tid = threadIdx.x;
    float4 x = ((const float4*)(xifft + (size_t)row * D_DIM))[tid];
    float4 r = ((const float4*)(recon + (size_t)row * D_DIM))[tid];
    float xx = x.x * x.x + x.y * x.y + x.z * x.z + x.w * x.w;
    float rr = r.x * r.x + r.y * r.y + r.z * r.z + r.w * r.w;
    float xr = x.x * r.x + x.y * r.y + x.z * r.z + x.w * r.w;
    float l1 = 0.f;
    {
        float d, ad;
        d = x.x - r.x; ad = fabsf(d); l1 += (ad < 1.0f) ? 0.5f * d * d : ad - 0.5f;
        d = x.y - r.y; ad = fabsf(d); l1 += (ad < 1.0f) ? 0.5f * d * d : ad - 0.5f;
        d = x.z - r.z; ad = fabsf(d); l1 += (ad < 1.0f) ? 0.5f * d * d : ad - 0.5f;
        d = x.w - r.w; ad = fabsf(d); l1 += (ad < 1.0f) ? 0.5f * d * d : ad - 0.5f;
    }
#pragma unroll
    for (int off = 32; off > 0; off >>= 1) {
        xx += __shfl_xor(xx, off); rr += __shfl_xor(rr, off);
        xr += __shfl_xor(xr, off); l1 += __shfl_xor(l1, off);
    }
    __shared__ float red[4][4];
    if ((tid & 63) == 0) {
        int w = tid >> 6;
        red[w][0] = xx; red[w][1] = rr; red[w][2] = xr; red[w][3] = l1;
    }
    __syncthreads();
    if (tid == 0) {
        xx = red[0][0] + red[1][0] + red[2][0] + red[3][0];
        rr = red[0][1] + red[1][1] + red[2][1] + red[3][1];
        xr = red[0][2] + red[1][2] + red[2][2] + red[3][2];
        l1 = red[0][3] + red[1][3] + red[2][3] + red[3][3];
        float nx = fmaxf(sqrtf(xx), 1e-12f);
        float nr = fmaxf(sqrtf(rr), 1e-12f);
        float cs = xr / (nx * nr);
        cs = fminf(fmaxf(cs, -1.0f + 1e-8f), 1.0f - 1e-8f);
        atomicAdd(gA, 1.0f - cs);
        const int b = row >> 11;
        const int s = row & (S_LEN - 1);
        if (s < Ndev[b]) {
            float sx = Sxx[row], st = Stt[row], sxtv = Sxt[row];
            float nxx = fmaxf(sqrtf(sx), 1e-12f);
            float ntt = fmaxf(sqrtf(st), 1e-12f);
            float sem = (sx / (nxx * nxx) + st / (ntt * ntt)
                         - 2.0f * sxtv / (nxx * ntt)) * (1.0f / D_DIM);
            atomicAdd(gB, 0.2f * (l1 * (1.0f / D_DIM)) + 0.2f * sem);
        }
    }
}

// ------------------------------------------------------------- final loss
__global__ void final_loss(const float* __restrict__ gA, const float* __restrict__ gB,
                           const int* __restrict__ Ndev, float* __restrict__ out)
{
    if (threadIdx.x == 0 && blockIdx.x == 0) {
        int K = 0;
        for (int b = 0; b < B_BATCH; b++) K += Ndev[b];
        float Kf = (float)K;
        float M = gA[0] * (1.0f / 16384.0f);
        out[(size_t)R_ROWS * D_DIM] = (0.6f * M * Kf + gB[0]) / (Kf + 1e-8f);
    }
}

// ---------------------------------------------------------------------------
extern "C" void kernel_launch(void* const* d_in, const int* in_sizes, int n_in,
                              void* d_out, int out_size, void* d_ws, size_t ws_size,
                              hipStream_t stream)
{
    (void)in_sizes; (void)n_in; (void)out_size; (void)ws_size;
    const int*   x       = (const int*)  d_in[0];
    const float* tok     = (const float*)d_in[1];
    const float* pos     = (const float*)d_in[2];
    const float* conv1_w = (const float*)d_in[3];
    const float* conv1_b = (const float*)d_in[4];
    const float* conv2_w = (const float*)d_in[5];
    const float* conv2_b = (const float*)d_in[6];
    const float* proj_w  = (const float*)d_in[7];
    const float* proj_b  = (const float*)d_in[8];
    const float* ph_w    = (const float*)d_in[9];
    const float* ph_b    = (const float*)d_in[10];
    const float* ln_g    = (const float*)d_in[11];
    const float* ln_b    = (const float*)d_in[12];
    float* out = (float*)d_out;

    char* ws = (char*)d_ws;
    int*   counts = (int*)(ws + 0);
    int*   Ndev   = (int*)(ws + 64);
    float* gA     = (float*)(ws + 128);
    float* gB     = (float*)(ws + 132);
    float* Sxx    = (float*)(ws + 1024);
    float* Stt    = (float*)(ws + 1024 + 65536);
    float* Sxt    = (float*)(ws + 1024 + 131072);
    const size_t BIG = 1ull << 20;
    const size_t BUF = (size_t)R_ROWS * D_DIM * sizeof(float);   // 67,108,864
    float*  bufA = (float*)(ws + BIG);
    float*  bufB = (float*)(ws + BIG + BUF);
    float*  bufC = (float*)(ws + BIG + 2 * BUF);                 // 134 MB region
    float2* Xc   = (float2*)bufC;

    hipMemsetAsync(ws, 0, 1ull << 20, stream);

    // h0 = token_emb[x] + pos_emb
    emb_kernel<<<R_ROWS, 256, 0, stream>>>(x, tok, pos, bufA);
    // h1 = gelu(conv1(h0)),  h2 = gelu(conv2(h1))
    gemm_conv<<<dim3(R_ROWS / 128, D_DIM / 128), 256, 0, stream>>>(bufA, conv1_w, conv1_b, bufB, 3, 1);
    gemm_conv<<<dim3(R_ROWS / 128, D_DIM / 128), 256, 0, stream>>>(bufB, conv2_w, conv2_b, bufA, 3, 1);
    // h = LN(h2)
    ln_kernel<<<R_ROWS, 256, 0, stream>>>(bufA, ln_g, ln_b, bufB, nullptr);
    // transpose [B,S,D] -> [B,D,S]
    transposeMN<<<dim3(D_DIM / 32, S_LEN / 32, B_BATCH), dim3(32, 8), 0, stream>>>(bufB, bufA, S_LEN, D_DIM);
    // forward FFT + complexity counts
    fft_fwd<<<BD_ROWS, 256, 0, stream>>>(bufA, Xc, counts);
    calc_n<<<1, 64, 0, stream>>>(counts, Ndev);
    // masked inverse FFT (real part), [B,D,S]
    fft_inv<<<BD_ROWS, 256, 0, stream>>>(Xc, Ndev, bufA);
    // transpose back [B,D,S] -> [B,S,D]  = x_ifft_raw
    transposeMN<<<dim3(S_LEN / 32, D_DIM / 32, B_BATCH), dim3(32, 8), 0, stream>>>(bufA, bufB, D_DIM, S_LEN);
    // proj_out = x_ifft_raw @ proj_w + proj_b   (= recon_target)
    gemm_conv<<<dim3(R_ROWS / 128, D_DIM / 128), 256, 0, stream>>>(bufB, proj_w, proj_b, bufA, 1, 0);
    // x_ifft = LN(proj_out): write to ws copy (bufC) and to d_out
    ln_kernel<<<R_ROWS, 256, 0, stream>>>(bufA, ln_g, ln_b, bufC, out);
    // ph-projection row stats (for sem term)
    phstats<<<dim3(R_ROWS / 128, D_DIM / 64), 256, 0, stream>>>(bufC, bufA, ph_w, ph_b, Sxx, Stt, Sxt);
    // per-row cos-sim / smooth-L1 / sem  -> masked accumulators
    row_stats<<<R_ROWS, 256, 0, stream>>>(bufC, bufA, Sxx, Stt, Sxt, Ndev, gA, gB);
    final_loss<<<1, 64, 0, stream>>>(gA, gB, Ndev, out);
}

// Round 2
// 1104.692 us; speedup vs baseline: 3.7908x; 3.7908x over previous
//
#include <hip/hip_runtime.h>
#include <math.h>

#define S_LEN 2048
#define D_DIM 1024
#define B_BATCH 8
#define R_ROWS (B_BATCH * S_LEN)    // 16384
#define BD_ROWS (B_BATCH * D_DIM)   // 8192
#define PAD_ROWS 2050               // 1 zero row + 2048 + 1 zero row per batch
#define PADTOT (B_BATCH * PAD_ROWS) // 16400

typedef unsigned short u16;
typedef unsigned int u32;
typedef __attribute__((ext_vector_type(8))) short bf16x8;
typedef __attribute__((ext_vector_type(4))) float f32x4;

__device__ __forceinline__ u16 f2bf(float f) {
    u32 x = __float_as_uint(f);
    u32 r = (x + 0x7fffu + ((x >> 16) & 1u)) >> 16;   // RNE
    return (u16)r;
}
__device__ __forceinline__ float bf2f(u16 u) {
    return __uint_as_float(((u32)u) << 16);
}
__device__ __forceinline__ float gelu_exact(float x) {
    return 0.5f * x * (1.0f + erff(x * 0.70710678118654752f));
}

#define GLDS(gsrc, ldst)                                                                   \
    __builtin_amdgcn_global_load_lds(                                                      \
        (const __attribute__((address_space(1))) u32*)(gsrc),                              \
        (__attribute__((address_space(3))) u32*)(ldst), 16, 0, 0)

// ----------------------------------------------------------- zero pad rows
__global__ __launch_bounds__(256) void zero_pads(u16* __restrict__ P0, u16* __restrict__ P1)
{
    const int bid = blockIdx.x;          // 0..31
    u16* P = (bid >= 16) ? P1 : P0;
    const int ridx = bid & 15;
    const int b = ridx >> 1;
    const size_t row = (size_t)b * PAD_ROWS + (size_t)(ridx & 1) * (PAD_ROWS - 1);
    ((uint2*)(P + row * D_DIM))[threadIdx.x] = make_uint2(0u, 0u);
}

// ----------------------------------------- weight convert+transpose to bf16
// in: W f32 [T][K=1024][N=1024]; out: WT bf16 [T][N][K]
__global__ __launch_bounds__(256) void wconv(const float* __restrict__ W, u16* __restrict__ WT)
{
    __shared__ float t[32][33];
    const int tap = blockIdx.z;
    const int n0 = blockIdx.x * 32, k0 = blockIdx.y * 32;
    const int tx = threadIdx.x, ty = threadIdx.y;
    const float* ip = W + (size_t)tap * D_DIM * D_DIM;
    u16* op = WT + (size_t)tap * D_DIM * D_DIM;
#pragma unroll
    for (int u = 0; u < 4; u++)
        t[ty + u * 8][tx] = ip[(size_t)(k0 + ty + u * 8) * D_DIM + n0 + tx];
    __syncthreads();
#pragma unroll
    for (int u = 0; u < 4; u++)
        op[(size_t)(n0 + ty + u * 8) * D_DIM + k0 + tx] = f2bf(t[tx][ty + u * 8]);
}

// ---------------------------------------------------------------- embedding
__global__ __launch_bounds__(256) void emb_kernel(
    const int* __restrict__ x, const float* __restrict__ tok,
    const float* __restrict__ pos, u16* __restrict__ P0)
{
    const int row = blockIdx.x;          // b*S + s
    const int tid = threadIdx.x;
    const int t = x[row];
    const int s = row & (S_LEN - 1);
    const int b = row >> 11;
    float4 a = ((const float4*)(tok + (size_t)t * D_DIM))[tid];
    float4 p = ((const float4*)(pos + (size_t)s * D_DIM))[tid];
    uint2 v;
    v.x = (u32)f2bf(a.x + p.x) | ((u32)f2bf(a.y + p.y) << 16);
    v.y = (u32)f2bf(a.z + p.z) | ((u32)f2bf(a.w + p.w) << 16);
    ((uint2*)(P0 + ((size_t)b * PAD_ROWS + 1 + s) * D_DIM))[tid] = v;
}

// ------------------------------------------------------- bf16 MFMA GEMM/conv
// C[row,col] = act(bias[col] + sum_tap sum_k A[row+tap-ofs, k] * WT[tap][col][k])
// m97 structure: 128x128 tile, BK=32, 4 waves (2x2), global_load_lds width 16.
__global__ __launch_bounds__(256, 2) void gemm_mfma(
    const u16* __restrict__ A, const u16* __restrict__ WT,
    const float* __restrict__ bias,
    float* __restrict__ outF, u16* __restrict__ outB,
    const float* __restrict__ ptbuf,
    float* __restrict__ Sxx, float* __restrict__ Stt, float* __restrict__ Sxt,
    int ntaps, int doGelu, int aPadded, int outBPadded)
{
    __shared__ u16 Abuf[128 * 32];
    __shared__ u16 Bbuf[128 * 32];
    const int tid = threadIdx.x;
    const int wid = tid >> 6, lane = tid & 63;
    const int wr = wid >> 1, wc = wid & 1;
    const int col0 = blockIdx.x * 128;
    const int row0 = blockIdx.y * 128;
    const int b = row0 >> 11;
    const int srow0 = row0 & (S_LEN - 1);
    const int l15 = lane & 15, l4 = lane >> 4;

    f32x4 acc[4][4];
#pragma unroll
    for (int i = 0; i < 4; i++)
#pragma unroll
        for (int j = 0; j < 4; j++) acc[i][j] = (f32x4){0.f, 0.f, 0.f, 0.f};

    for (int tap = 0; tap < ntaps; ++tap) {
        const size_t aBase = aPadded ? ((size_t)(b * PAD_ROWS + srow0 + tap) << 10)
                                     : ((size_t)row0 << 10);
        const u16* Wt = WT + ((size_t)tap << 20) + ((size_t)col0 << 10);
        for (int k0 = 0; k0 < D_DIM; k0 += 32) {
#pragma unroll
            for (int c = 0; c < 2; c++) {
                const int chunk = wid + c * 4;
                const int off = chunk * 1024 + lane * 16;   // byte offset in 8KB tile
                const int r = off >> 6;                     // tile row (64B per row)
                const int cb = off & 63;                    // byte within row
                GLDS(A + aBase + ((size_t)r << 10) + (size_t)(k0 + (cb >> 1)),
                     (char*)Abuf + off);
                GLDS(Wt + ((size_t)r << 10) + (size_t)(k0 + (cb >> 1)),
                     (char*)Bbuf + off);
            }
            __syncthreads();
            bf16x8 af[4], bfr[4];
#pragma unroll
            for (int mi = 0; mi < 4; mi++)
                af[mi] = *(const bf16x8*)&Abuf[(wr * 64 + mi * 16 + l15) * 32 + l4 * 8];
#pragma unroll
            for (int ni = 0; ni < 4; ni++)
                bfr[ni] = *(const bf16x8*)&Bbuf[(wc * 64 + ni * 16 + l15) * 32 + l4 * 8];
#pragma unroll
            for (int mi = 0; mi < 4; mi++)
#pragma unroll
                for (int ni = 0; ni < 4; ni++)
                    acc[mi][ni] = __builtin_amdgcn_mfma_f32_16x16x32_bf16(
                        af[mi], bfr[ni], acc[mi][ni], 0, 0, 0);
            __syncthreads();
        }
    }

    float bv[4];
#pragma unroll
    for (int ni = 0; ni < 4; ni++) bv[ni] = bias[col0 + wc * 64 + ni * 16 + l15];

    if (Sxx) {
        // ph mode: px = acc+bias, pt from ptbuf; per-row sums via 16-lane reduce
#pragma unroll
        for (int mi = 0; mi < 4; mi++) {
#pragma unroll
            for (int reg = 0; reg < 4; reg++) {
                const int row = row0 + wr * 64 + mi * 16 + l4 * 4 + reg;
                float sxx = 0.f, stt = 0.f, sxt = 0.f;
#pragma unroll
                for (int ni = 0; ni < 4; ni++) {
                    const int col = col0 + wc * 64 + ni * 16 + l15;
                    float px = acc[mi][ni][reg] + bv[ni];
                    float pt = ptbuf[(size_t)row * D_DIM + col];
                    sxx = fmaf(px, px, sxx);
                    stt = fmaf(pt, pt, stt);
                    sxt = fmaf(px, pt, sxt);
                }
#pragma unroll
                for (int off = 1; off < 16; off <<= 1) {
                    sxx += __shfl_xor(sxx, off);
                    stt += __shfl_xor(stt, off);
                    sxt += __shfl_xor(sxt, off);
                }
                if (l15 == 0) {
                    atomicAdd(&Sxx[row], sxx);
                    atomicAdd(&Stt[row], stt);
                    atomicAdd(&Sxt[row], sxt);
                }
            }
        }
        return;
    }

#pragma unroll
    for (int mi = 0; mi < 4; mi++) {
#pragma unroll
        for (int ni = 0; ni < 4; ni++) {
#pragma unroll
            for (int reg = 0; reg < 4; reg++) {
                const int row = row0 + wr * 64 + mi * 16 + l4 * 4 + reg;
                const int col = col0 + wc * 64 + ni * 16 + l15;
                float v = acc[mi][ni][reg] + bv[ni];
                if (doGelu) v = gelu_exact(v);
                if (outF) outF[(size_t)row * D_DIM + col] = v;
                if (outB) {
                    const size_t orow = outBPadded
                        ? ((size_t)(row >> 11) * PAD_ROWS + 1 + (size_t)(row & (S_LEN - 1)))
                        : (size_t)row;
                    outB[orow * D_DIM + col] = f2bf(v);
                }
            }
        }
    }
}

// -------------------------------------------------------- layernorm (bf16 in)
__global__ __launch_bounds__(256) void ln_bf(
    const u16* __restrict__ in, const float* __restrict__ g,
    const float* __restrict__ beta, float* __restrict__ out)
{
    const int row = blockIdx.x;
    const int tid = threadIdx.x;
    uint2 raw = ((const uint2*)(in + (size_t)row * D_DIM))[tid];
    float v0 = bf2f((u16)(raw.x & 0xffff)), v1 = bf2f((u16)(raw.x >> 16));
    float v2 = bf2f((u16)(raw.y & 0xffff)), v3 = bf2f((u16)(raw.y >> 16));
    float s = v0 + v1 + v2 + v3;
    float s2 = v0 * v0 + v1 * v1 + v2 * v2 + v3 * v3;
#pragma unroll
    for (int off = 32; off > 0; off >>= 1) {
        s += __shfl_xor(s, off);
        s2 += __shfl_xor(s2, off);
    }
    __shared__ float red[8];
    if ((tid & 63) == 0) { red[(tid >> 6) * 2] = s; red[(tid >> 6) * 2 + 1] = s2; }
    __syncthreads();
    s = red[0] + red[2] + red[4] + red[6];
    s2 = red[1] + red[3] + red[5] + red[7];
    const float m = s * (1.0f / D_DIM);
    const float var = s2 * (1.0f / D_DIM) - m * m;
    const float rs = rsqrtf(var + 1e-5f);
    float4 gg = ((const float4*)g)[tid];
    float4 bb = ((const float4*)beta)[tid];
    float4 o;
    o.x = (v0 - m) * rs * gg.x + bb.x;
    o.y = (v1 - m) * rs * gg.y + bb.y;
    o.z = (v2 - m) * rs * gg.z + bb.z;
    o.w = (v3 - m) * rs * gg.w + bb.w;
    ((float4*)(out + (size_t)row * D_DIM))[tid] = o;
}

// ------------------------------------------- layernorm (f32 in, f32+bf16 out)
__global__ __launch_bounds__(256) void ln_f32(
    const float* __restrict__ in, const float* __restrict__ g,
    const float* __restrict__ beta, float* __restrict__ outF, u16* __restrict__ outB)
{
    const int row = blockIdx.x;
    const int tid = threadIdx.x;
    float4 v = ((const float4*)(in + (size_t)row * D_DIM))[tid];
    float s = v.x + v.y + v.z + v.w;
    float s2 = v.x * v.x + v.y * v.y + v.z * v.z + v.w * v.w;
#pragma unroll
    for (int off = 32; off > 0; off >>= 1) {
        s += __shfl_xor(s, off);
        s2 += __shfl_xor(s2, off);
    }
    __shared__ float red[8];
    if ((tid & 63) == 0) { red[(tid >> 6) * 2] = s; red[(tid >> 6) * 2 + 1] = s2; }
    __syncthreads();
    s = red[0] + red[2] + red[4] + red[6];
    s2 = red[1] + red[3] + red[5] + red[7];
    const float m = s * (1.0f / D_DIM);
    const float var = s2 * (1.0f / D_DIM) - m * m;
    const float rs = rsqrtf(var + 1e-5f);
    float4 gg = ((const float4*)g)[tid];
    float4 bb = ((const float4*)beta)[tid];
    float4 o;
    o.x = (v.x - m) * rs * gg.x + bb.x;
    o.y = (v.y - m) * rs * gg.y + bb.y;
    o.z = (v.z - m) * rs * gg.z + bb.z;
    o.w = (v.w - m) * rs * gg.w + bb.w;
    ((float4*)(outF + (size_t)row * D_DIM))[tid] = o;
    uint2 pb;
    pb.x = (u32)f2bf(o.x) | ((u32)f2bf(o.y) << 16);
    pb.y = (u32)f2bf(o.z) | ((u32)f2bf(o.w) << 16);
    ((uint2*)(outB + (size_t)row * D_DIM))[tid] = pb;
}

// ---------------------------------------------- transpose [B][M][N]->[B][N][M]
__global__ __launch_bounds__(256) void transposeMN(
    const float* __restrict__ in, float* __restrict__ out, int M, int N)
{
    __shared__ float t[32][33];
    const int b = blockIdx.z;
    const int n0 = blockIdx.x * 32, m0 = blockIdx.y * 32;
    const int tx = threadIdx.x, ty = threadIdx.y;
    const float* ip = in + (size_t)b * M * N;
    float* op = out + (size_t)b * M * N;
#pragma unroll
    for (int u = 0; u < 4; u++)
        t[ty + u * 8][tx] = ip[(size_t)(m0 + ty + u * 8) * N + n0 + tx];
    __syncthreads();
#pragma unroll
    for (int u = 0; u < 4; u++)
        op[(size_t)(n0 + ty + u * 8) * M + m0 + tx] = t[tx][ty + u * 8];
}

// ------------------------------------- transpose + f32->bf16  [B][M][N]->[B][N][M]
__global__ __launch_bounds__(256) void transposeMN_b(
    const float* __restrict__ in, u16* __restrict__ out, int M, int N)
{
    __shared__ float t[32][33];
    const int b = blockIdx.z;
    const int n0 = blockIdx.x * 32, m0 = blockIdx.y * 32;
    const int tx = threadIdx.x, ty = threadIdx.y;
    const float* ip = in + (size_t)b * M * N;
    u16* op = out + (size_t)b * M * N;
#pragma unroll
    for (int u = 0; u < 4; u++)
        t[ty + u * 8][tx] = ip[(size_t)(m0 + ty + u * 8) * N + n0 + tx];
    __syncthreads();
#pragma unroll
    for (int u = 0; u < 4; u++)
        op[(size_t)(n0 + ty + u * 8) * M + m0 + tx] = f2bf(t[tx][ty + u * 8]);
}

// ------------------------------------------------------------- forward FFT
// one block per (b,d) row of [B,D,S]; stores half-spectrum k<1024 (real input
// => X[S-k]=conj(X[k])); counts full spectrum via the stored LDS copy.
__global__ __launch_bounds__(256) void fft_fwd(
    const float* __restrict__ in, float2* __restrict__ X, int* __restrict__ counts)
{
    __shared__ float re[2048], im[2048], twr[1024], twi[1024];
    __shared__ float redf[4];
    __shared__ int redi[4];
    const int tid = threadIdx.x;
    const int row = blockIdx.x;          // b*D + d
    const float* src = in + (size_t)row * S_LEN;
#pragma unroll
    for (int u = 0; u < 4; u++) {
        int j = tid + u * 256;
        float ang = -3.14159265358979f * (float)j * (1.0f / 1024.0f);
        float sn, cs; __sincosf(ang, &sn, &cs);
        twr[j] = cs; twi[j] = sn;
    }
#pragma unroll
    for (int u = 0; u < 8; u++) {
        int i = tid + u * 256;
        float v = src[i];
        int r = __brev((unsigned)i) >> 21;
        re[r] = v; im[r] = 0.0f;
    }
    __syncthreads();
    for (int st = 1; st <= 11; ++st) {
        const int mh = 1 << (st - 1);
#pragma unroll
        for (int u = 0; u < 4; u++) {
            int tb = tid + u * 256;
            int gidx = tb >> (st - 1);
            int j = tb & (mh - 1);
            int i1 = (gidx << st) + j;
            int i2 = i1 + mh;
            int ti = j << (11 - st);
            float wr = twr[ti], wi = twi[ti];
            float xr = re[i2], xi = im[i2];
            float vr = xr * wr - xi * wi;
            float vi = xr * wi + xi * wr;
            float ur = re[i1], ui = im[i1];
            re[i1] = ur + vr; im[i1] = ui + vi;
            re[i2] = ur - vr; im[i2] = ui - vi;
        }
        __syncthreads();
    }
    float2* dst = X + (size_t)row * 1024;
    float lmax = 0.0f;
#pragma unroll
    for (int u = 0; u < 8; u++) {
        int k = tid + u * 256;
        float xr = re[k], xi = im[k];
        lmax = fmaxf(lmax, xr * xr + xi * xi);
    }
#pragma unroll
    for (int off = 32; off > 0; off >>= 1) lmax = fmaxf(lmax, __shfl_xor(lmax, off));
    if ((tid & 63) == 0) redf[tid >> 6] = lmax;
    __syncthreads();
    const float bmax = fmaxf(fmaxf(redf[0], redf[1]), fmaxf(redf[2], redf[3]));
    const float thr = 0.01f * bmax;
#pragma unroll
    for (int u = 0; u < 4; u++) {
        int k = tid + u * 256;
        dst[k] = make_float2(re[k], im[k]);
    }
    int lc = 0;
#pragma unroll
    for (int u = 0; u < 8; u++) {
        int k = tid + u * 256;
        float xr = re[k], xi = im[k];
        lc += ((xr * xr + xi * xi) > thr) ? 1 : 0;
    }
#pragma unroll
    for (int off = 32; off > 0; off >>= 1) lc += __shfl_xor(lc, off);
    __syncthreads();
    if ((tid & 63) == 0) redi[tid >> 6] = lc;
    __syncthreads();
    if (tid == 0)
        atomicAdd(&counts[row >> 10], redi[0] + redi[1] + redi[2] + redi[3]);
}

// ------------------------------------------------------------- N from counts
__global__ void calc_n(const int* __restrict__ counts, int* __restrict__ Ndev)
{
    if (threadIdx.x == 0 && blockIdx.x == 0) {
        for (int b = 0; b < B_BATCH; b++) {
            float c = (float)counts[b] * (1.0f / 2097152.0f);  // /(S*D)
            float cr = 0.5f * (1.0f - c);
            cr = fminf(fmaxf(cr, 0.1f), 1.0f);
            int n = (int)(cr * 2048.0f);
            n = n < 1 ? 1 : (n > S_LEN ? S_LEN : n);
            Ndev[b] = n;
        }
    }
}

// ------------------------------------------------------- masked inverse FFT
__global__ __launch_bounds__(256) void fft_inv(
    const float2* __restrict__ X, const int* __restrict__ Ndev,
    float* __restrict__ out)
{
    __shared__ float re[2048], im[2048], twr[1024], twi[1024];
    const int tid = threadIdx.x;
    const int row = blockIdx.x;          // b*D + d
    const int Nb = Ndev[row >> 10];      // guaranteed <= 1023
    const float2* src = X + (size_t)row * 1024;
#pragma unroll
    for (int u = 0; u < 4; u++) {
        int j = tid + u * 256;
        float ang = 3.14159265358979f * (float)j * (1.0f / 1024.0f);
        float sn, cs; __sincosf(ang, &sn, &cs);
        twr[j] = cs; twi[j] = sn;
    }
#pragma unroll
    for (int u = 0; u < 8; u++) {
        int k = tid + u * 256;
        float2 v = (k < Nb) ? src[k] : make_float2(0.f, 0.f);
        int r = __brev((unsigned)k) >> 21;
        re[r] = v.x; im[r] = v.y;
    }
    __syncthreads();
    for (int st = 1; st <= 11; ++st) {
        const int mh = 1 << (st - 1);
#pragma unroll
        for (int u = 0; u < 4; u++) {
            int tb = tid + u * 256;
            int gidx = tb >> (st - 1);
            int j = tb & (mh - 1);
            int i1 = (gidx << st) + j;
            int i2 = i1 + mh;
            int ti = j << (11 - st);
            float wr = twr[ti], wi = twi[ti];
            float xr = re[i2], xi = im[i2];
            float vr = xr * wr - xi * wi;
            float vi = xr * wi + xi * wr;
            float ur = re[i1], ui = im[i1];
            re[i1] = ur + vr; im[i1] = ui + vi;
            re[i2] = ur - vr; im[i2] = ui - vi;
        }
        __syncthreads();
    }
    float* dst = out + (size_t)row * S_LEN;
#pragma unroll
    for (int u = 0; u < 8; u++) {
        int k = tid + u * 256;
        dst[k] = re[k] * (1.0f / 2048.0f);
    }
}

// ------------------------------------------------- per-row loss statistics
__global__ __launch_bounds__(256) void row_stats(
    const float* __restrict__ xifft, const float* __restrict__ recon,
    const float* __restrict__ Sxx, const float* __restrict__ Stt,
    const float* __restrict__ Sxt, const int* __restrict__ Ndev,
    float* __restrict__ gA, float* __restrict__ gB)
{
    const int row = blockIdx.x;
    const int tid = threadIdx.x;
    float4 x = ((const float4*)(xifft + (size_t)row * D_DIM))[tid];
    float4 r = ((const float4*)(recon + (size_t)row * D_DIM))[tid];
    float xx = x.x * x.x + x.y * x.y + x.z * x.z + x.w * x.w;
    float rr = r.x * r.x + r.y * r.y + r.z * r.z + r.w * r.w;
    float xr = x.x * r.x + x.y * r.y + x.z * r.z + x.w * r.w;
    float l1 = 0.f;
    {
        float d, ad;
        d = x.x - r.x; ad = fabsf(d); l1 += (ad < 1.0f) ? 0.5f * d * d : ad - 0.5f;
        d = x.y - r.y; ad = fabsf(d); l1 += (ad < 1.0f) ? 0.5f * d * d : ad - 0.5f;
        d = x.z - r.z; ad = fabsf(d); l1 += (ad < 1.0f) ? 0.5f * d * d : ad - 0.5f;
        d = x.w - r.w; ad = fabsf(d); l1 += (ad < 1.0f) ? 0.5f * d * d : ad - 0.5f;
    }
#pragma unroll
    for (int off = 32; off > 0; off >>= 1) {
        xx += __shfl_xor(xx, off); rr += __shfl_xor(rr, off);
        xr += __shfl_xor(xr, off); l1 += __shfl_xor(l1, off);
    }
    __shared__ float red[4][4];
    if ((tid & 63) == 0) {
        int w = tid >> 6;
        red[w][0] = xx; red[w][1] = rr; red[w][2] = xr; red[w][3] = l1;
    }
    __syncthreads();
    if (tid == 0) {
        xx = red[0][0] + red[1][0] + red[2][0] + red[3][0];
        rr = red[0][1] + red[1][1] + red[2][1] + red[3][1];
        xr = red[0][2] + red[1][2] + red[2][2] + red[3][2];
        l1 = red[0][3] + red[1][3] + red[2][3] + red[3][3];
        float nx = fmaxf(sqrtf(xx), 1e-12f);
        float nr = fmaxf(sqrtf(rr), 1e-12f);
        float cs = xr / (nx * nr);
        cs = fminf(fmaxf(cs, -1.0f + 1e-8f), 1.0f - 1e-8f);
        atomicAdd(gA, 1.0f - cs);
        const int b = row >> 11;
        const int s = row & (S_LEN - 1);
        if (s < Ndev[b]) {
            float sx = Sxx[row], st = Stt[row], sxtv = Sxt[row];
            float nxx = fmaxf(sqrtf(sx), 1e-12f);
            float ntt = fmaxf(sqrtf(st), 1e-12f);
            float sem = (sx / (nxx * nxx) + st / (ntt * ntt)
                         - 2.0f * sxtv / (nxx * ntt)) * (1.0f / D_DIM);
            atomicAdd(gB, 0.2f * (l1 * (1.0f / D_DIM)) + 0.2f * sem);
        }
    }
}

// ------------------------------------------------------------- final loss
__global__ void final_loss(const float* __restrict__ gA, const float* __restrict__ gB,
                           const int* __restrict__ Ndev, float* __restrict__ out)
{
    if (threadIdx.x == 0 && blockIdx.x == 0) {
        int K = 0;
        for (int b = 0; b < B_BATCH; b++) K += Ndev[b];
        float Kf = (float)K;
        float M = gA[0] * (1.0f / 16384.0f);
        out[(size_t)R_ROWS * D_DIM] = (0.6f * M * Kf + gB[0]) / (Kf + 1e-8f);
    }
}

// ---------------------------------------------------------------------------
extern "C" void kernel_launch(void* const* d_in, const int* in_sizes, int n_in,
                              void* d_out, int out_size, void* d_ws, size_t ws_size,
                              hipStream_t stream)
{
    (void)in_sizes; (void)n_in; (void)out_size; (void)ws_size;
    const int*   x       = (const int*)  d_in[0];
    const float* tok     = (const float*)d_in[1];
    const float* pos     = (const float*)d_in[2];
    const float* conv1_w = (const float*)d_in[3];
    const float* conv1_b = (const float*)d_in[4];
    const float* conv2_w = (const float*)d_in[5];
    const float* conv2_b = (const float*)d_in[6];
    const float* proj_w  = (const float*)d_in[7];
    const float* proj_b  = (const float*)d_in[8];
    const float* ph_w    = (const float*)d_in[9];
    const float* ph_b    = (const float*)d_in[10];
    const float* ln_g    = (const float*)d_in[11];
    const float* ln_b    = (const float*)d_in[12];
    float* out = (float*)d_out;

    char* ws = (char*)d_ws;
    int*   counts = (int*)(ws);
    int*   Ndev   = (int*)(ws + 64);
    float* gA     = (float*)(ws + 128);
    float* gB     = (float*)(ws + 132);
    float* Sxx    = (float*)(ws + 4096);
    float* Stt    = (float*)(ws + 4096 + 65536);
    float* Sxt    = (float*)(ws + 4096 + 131072);
    const size_t MB = 1ull << 20;
    u16*   WT   = (u16*)(ws + 1 * MB);      // 16 MB (8 matrices of 1M bf16)
    u16*   P0   = (u16*)(ws + 17 * MB);     // 32.03 MB padded bf16 activations
    u16*   P1   = (u16*)(ws + 50 * MB);     // 32.03 MB
    float* F32A = (float*)(ws + 83 * MB);   // 64 MB
    float* F32B = (float*)(ws + 148 * MB);  // 64 MB (ends at 212 MB)

    hipMemsetAsync(ws, 0, MB, stream);
    zero_pads<<<32, 256, 0, stream>>>(P0, P1);
    wconv<<<dim3(32, 32, 3), dim3(32, 8), 0, stream>>>(conv1_w, WT);
    wconv<<<dim3(32, 32, 3), dim3(32, 8), 0, stream>>>(conv2_w, WT + 3u * (1u << 20));
    wconv<<<dim3(32, 32, 1), dim3(32, 8), 0, stream>>>(proj_w, WT + 6u * (1u << 20));
    wconv<<<dim3(32, 32, 1), dim3(32, 8), 0, stream>>>(ph_w, WT + 7u * (1u << 20));
    // h0 (padded bf16)
    emb_kernel<<<R_ROWS, 256, 0, stream>>>(x, tok, pos, P0);
    // h1 = gelu(conv1(h0)) -> P1 padded bf16
    gemm_mfma<<<dim3(8, 128), 256, 0, stream>>>(P0, WT, conv1_b, nullptr, P1,
        nullptr, nullptr, nullptr, nullptr, 3, 1, 1, 1);
    // h2 = gelu(conv2(h1)) -> P0 flat bf16
    gemm_mfma<<<dim3(8, 128), 256, 0, stream>>>(P1, WT + 3u * (1u << 20), conv2_b, nullptr, P0,
        nullptr, nullptr, nullptr, nullptr, 3, 1, 1, 0);
    // h = LN(h2) -> F32A
    ln_bf<<<R_ROWS, 256, 0, stream>>>(P0, ln_g, ln_b, F32A);
    // [B,S,D] -> [B,D,S]
    transposeMN<<<dim3(32, 64, 8), dim3(32, 8), 0, stream>>>(F32A, F32B, S_LEN, D_DIM);
    // forward FFT (half-spectrum into F32A region) + complexity counts
    fft_fwd<<<BD_ROWS, 256, 0, stream>>>(F32B, (float2*)F32A, counts);
    calc_n<<<1, 64, 0, stream>>>(counts, Ndev);
    // masked inverse FFT -> F32B [B,D,S]
    fft_inv<<<BD_ROWS, 256, 0, stream>>>((const float2*)F32A, Ndev, F32B);
    // [B,D,S] -> [B,S,D] bf16 (x_ifft_raw) -> P0 flat
    transposeMN_b<<<dim3(64, 32, 8), dim3(32, 8), 0, stream>>>(F32B, P0, D_DIM, S_LEN);
    // proj_out = x_ifft_raw @ proj_w + b  -> F32A (recon, f32) + P1 (bf16)
    gemm_mfma<<<dim3(8, 128), 256, 0, stream>>>(P0, WT + 6u * (1u << 20), proj_b, F32A, P1,
        nullptr, nullptr, nullptr, nullptr, 1, 0, 0, 0);
    // x_ifft = LN(proj_out) -> d_out (f32) + P0 (bf16)
    ln_f32<<<R_ROWS, 256, 0, stream>>>(F32A, ln_g, ln_b, out, P0);
    // pt = recon @ ph_w + b -> F32B
    gemm_mfma<<<dim3(8, 128), 256, 0, stream>>>(P1, WT + 7u * (1u << 20), ph_b, F32B, nullptr,
        nullptr, nullptr, nullptr, nullptr, 1, 0, 0, 0);
    // px = x_ifft @ ph_w + b; fused row stats vs pt
    gemm_mfma<<<dim3(8, 128), 256, 0, stream>>>(P0, WT + 7u * (1u << 20), ph_b, nullptr, nullptr,
        F32B, Sxx, Stt, Sxt, 1, 0, 0, 0);
    // loss accumulation
    row_stats<<<R_ROWS, 256, 0, stream>>>(out, F32A, Sxx, Stt, Sxt, Ndev, gA, gB);
    final_loss<<<1, 64, 0, stream>>>(gA, gB, Ndev, out);
}

// Round 3
// 760.270 us; speedup vs baseline: 5.5082x; 1.4530x over previous
//
#include <hip/hip_runtime.h>
#include <math.h>

#define S_LEN 2048
#define D_DIM 1024
#define B_BATCH 8
#define R_ROWS (B_BATCH * S_LEN)    // 16384
#define BD_ROWS (B_BATCH * D_DIM)   // 8192
#define PAD_ROWS 2050               // 1 zero row + 2048 + 1 zero row per batch

typedef unsigned short u16;
typedef unsigned int u32;
typedef __attribute__((ext_vector_type(8))) short bf16x8;
typedef __attribute__((ext_vector_type(4))) float f32x4;

__device__ __forceinline__ u16 f2bf(float f) {
    u32 x = __float_as_uint(f);
    u32 r = (x + 0x7fffu + ((x >> 16) & 1u)) >> 16;   // RNE
    return (u16)r;
}
__device__ __forceinline__ float bf2f(u16 u) {
    return __uint_as_float(((u32)u) << 16);
}
__device__ __forceinline__ float gelu_exact(float x) {
    return 0.5f * x * (1.0f + erff(x * 0.70710678118654752f));
}

#define GLDS(gsrc, ldst)                                                                   \
    __builtin_amdgcn_global_load_lds(                                                      \
        (const __attribute__((address_space(1))) u32*)(gsrc),                              \
        (__attribute__((address_space(3))) u32*)(ldst), 16, 0, 0)

// ----------------------------------------------------------- zero pad rows
__global__ __launch_bounds__(256) void zero_pads(u16* __restrict__ P0, u16* __restrict__ P1)
{
    const int bid = blockIdx.x;          // 0..31
    u16* P = (bid >= 16) ? P1 : P0;
    const int ridx = bid & 15;
    const int b = ridx >> 1;
    const size_t row = (size_t)b * PAD_ROWS + (size_t)(ridx & 1) * (PAD_ROWS - 1);
    ((uint2*)(P + row * D_DIM))[threadIdx.x] = make_uint2(0u, 0u);
}

// ----------------------------------------- weight convert+transpose to bf16
// in: W f32 [T][K=1024][N=1024]; out: WT bf16 [T][N][K]
__global__ __launch_bounds__(256) void wconv(const float* __restrict__ W, u16* __restrict__ WT)
{
    __shared__ float t[32][33];
    const int tap = blockIdx.z;
    const int n0 = blockIdx.x * 32, k0 = blockIdx.y * 32;
    const int tx = threadIdx.x, ty = threadIdx.y;
    const float* ip = W + (size_t)tap * D_DIM * D_DIM;
    u16* op = WT + (size_t)tap * D_DIM * D_DIM;
#pragma unroll
    for (int u = 0; u < 4; u++)
        t[ty + u * 8][tx] = ip[(size_t)(k0 + ty + u * 8) * D_DIM + n0 + tx];
    __syncthreads();
#pragma unroll
    for (int u = 0; u < 4; u++)
        op[(size_t)(n0 + ty + u * 8) * D_DIM + k0 + tx] = f2bf(t[tx][ty + u * 8]);
}

// ---------------------------------------------------------------- embedding
__global__ __launch_bounds__(256) void emb_kernel(
    const int* __restrict__ x, const float* __restrict__ tok,
    const float* __restrict__ pos, u16* __restrict__ P0)
{
    const int row = blockIdx.x;          // b*S + s
    const int tid = threadIdx.x;
    const int t = x[row];
    const int s = row & (S_LEN - 1);
    const int b = row >> 11;
    float4 a = ((const float4*)(tok + (size_t)t * D_DIM))[tid];
    float4 p = ((const float4*)(pos + (size_t)s * D_DIM))[tid];
    uint2 v;
    v.x = (u32)f2bf(a.x + p.x) | ((u32)f2bf(a.y + p.y) << 16);
    v.y = (u32)f2bf(a.z + p.z) | ((u32)f2bf(a.w + p.w) << 16);
    ((uint2*)(P0 + ((size_t)b * PAD_ROWS + 1 + s) * D_DIM))[tid] = v;
}

// ------------------------------------------------------- bf16 MFMA GEMM/conv
__global__ __launch_bounds__(256, 2) void gemm_mfma(
    const u16* __restrict__ A, const u16* __restrict__ WT,
    const float* __restrict__ bias,
    float* __restrict__ outF, u16* __restrict__ outB,
    const float* __restrict__ ptbuf,
    float* __restrict__ Sxx, float* __restrict__ Stt, float* __restrict__ Sxt,
    int ntaps, int doGelu, int aPadded, int outBPadded)
{
    __shared__ u16 Abuf[128 * 32];
    __shared__ u16 Bbuf[128 * 32];
    const int tid = threadIdx.x;
    const int wid = tid >> 6, lane = tid & 63;
    const int wr = wid >> 1, wc = wid & 1;
    const int col0 = blockIdx.x * 128;
    const int row0 = blockIdx.y * 128;
    const int b = row0 >> 11;
    const int srow0 = row0 & (S_LEN - 1);
    const int l15 = lane & 15, l4 = lane >> 4;

    f32x4 acc[4][4];
#pragma unroll
    for (int i = 0; i < 4; i++)
#pragma unroll
        for (int j = 0; j < 4; j++) acc[i][j] = (f32x4){0.f, 0.f, 0.f, 0.f};

    for (int tap = 0; tap < ntaps; ++tap) {
        const size_t aBase = aPadded ? ((size_t)(b * PAD_ROWS + srow0 + tap) << 10)
                                     : ((size_t)row0 << 10);
        const u16* Wt = WT + ((size_t)tap << 20) + ((size_t)col0 << 10);
        for (int k0 = 0; k0 < D_DIM; k0 += 32) {
#pragma unroll
            for (int c = 0; c < 2; c++) {
                const int chunk = wid + c * 4;
                const int off = chunk * 1024 + lane * 16;   // byte offset in 8KB tile
                const int r = off >> 6;
                const int cb = off & 63;
                GLDS(A + aBase + ((size_t)r << 10) + (size_t)(k0 + (cb >> 1)),
                     (char*)Abuf + off);
                GLDS(Wt + ((size_t)r << 10) + (size_t)(k0 + (cb >> 1)),
                     (char*)Bbuf + off);
            }
            __syncthreads();
            bf16x8 af[4], bfr[4];
#pragma unroll
            for (int mi = 0; mi < 4; mi++)
                af[mi] = *(const bf16x8*)&Abuf[(wr * 64 + mi * 16 + l15) * 32 + l4 * 8];
#pragma unroll
            for (int ni = 0; ni < 4; ni++)
                bfr[ni] = *(const bf16x8*)&Bbuf[(wc * 64 + ni * 16 + l15) * 32 + l4 * 8];
#pragma unroll
            for (int mi = 0; mi < 4; mi++)
#pragma unroll
                for (int ni = 0; ni < 4; ni++)
                    acc[mi][ni] = __builtin_amdgcn_mfma_f32_16x16x32_bf16(
                        af[mi], bfr[ni], acc[mi][ni], 0, 0, 0);
            __syncthreads();
        }
    }

    float bv[4];
#pragma unroll
    for (int ni = 0; ni < 4; ni++) bv[ni] = bias[col0 + wc * 64 + ni * 16 + l15];

    if (Sxx) {
#pragma unroll
        for (int mi = 0; mi < 4; mi++) {
#pragma unroll
            for (int reg = 0; reg < 4; reg++) {
                const int row = row0 + wr * 64 + mi * 16 + l4 * 4 + reg;
                float sxx = 0.f, stt = 0.f, sxt = 0.f;
#pragma unroll
                for (int ni = 0; ni < 4; ni++) {
                    const int col = col0 + wc * 64 + ni * 16 + l15;
                    float px = acc[mi][ni][reg] + bv[ni];
                    float pt = ptbuf[(size_t)row * D_DIM + col];
                    sxx = fmaf(px, px, sxx);
                    stt = fmaf(pt, pt, stt);
                    sxt = fmaf(px, pt, sxt);
                }
#pragma unroll
                for (int off = 1; off < 16; off <<= 1) {
                    sxx += __shfl_xor(sxx, off);
                    stt += __shfl_xor(stt, off);
                    sxt += __shfl_xor(sxt, off);
                }
                if (l15 == 0) {
                    atomicAdd(&Sxx[row], sxx);
                    atomicAdd(&Stt[row], stt);
                    atomicAdd(&Sxt[row], sxt);
                }
            }
        }
        return;
    }

#pragma unroll
    for (int mi = 0; mi < 4; mi++) {
#pragma unroll
        for (int ni = 0; ni < 4; ni++) {
#pragma unroll
            for (int reg = 0; reg < 4; reg++) {
                const int row = row0 + wr * 64 + mi * 16 + l4 * 4 + reg;
                const int col = col0 + wc * 64 + ni * 16 + l15;
                float v = acc[mi][ni][reg] + bv[ni];
                if (doGelu) v = gelu_exact(v);
                if (outF) outF[(size_t)row * D_DIM + col] = v;
                if (outB) {
                    const size_t orow = outBPadded
                        ? ((size_t)(row >> 11) * PAD_ROWS + 1 + (size_t)(row & (S_LEN - 1)))
                        : (size_t)row;
                    outB[orow * D_DIM + col] = f2bf(v);
                }
            }
        }
    }
}

// ------------------------------------------- per-row LN stats (mean, rstd)
__global__ __launch_bounds__(256) void ln_stats(
    const u16* __restrict__ in, float2* __restrict__ stats)
{
    const int row = blockIdx.x;
    const int tid = threadIdx.x;
    uint2 raw = ((const uint2*)(in + (size_t)row * D_DIM))[tid];
    float v0 = bf2f((u16)(raw.x & 0xffff)), v1 = bf2f((u16)(raw.x >> 16));
    float v2 = bf2f((u16)(raw.y & 0xffff)), v3 = bf2f((u16)(raw.y >> 16));
    float s = v0 + v1 + v2 + v3;
    float s2 = v0 * v0 + v1 * v1 + v2 * v2 + v3 * v3;
#pragma unroll
    for (int off = 32; off > 0; off >>= 1) {
        s += __shfl_xor(s, off);
        s2 += __shfl_xor(s2, off);
    }
    __shared__ float red[8];
    if ((tid & 63) == 0) { red[(tid >> 6) * 2] = s; red[(tid >> 6) * 2 + 1] = s2; }
    __syncthreads();
    if (tid == 0) {
        s = red[0] + red[2] + red[4] + red[6];
        s2 = red[1] + red[3] + red[5] + red[7];
        const float m = s * (1.0f / D_DIM);
        const float var = s2 * (1.0f / D_DIM) - m * m;
        stats[row] = make_float2(m, rsqrtf(var + 1e-5f));
    }
}

// ------------------- fused LN + transpose: bf16 [B,S,D] -> f32 [B,D,S]
__global__ __launch_bounds__(256) void transposeLN(
    const u16* __restrict__ in, const float2* __restrict__ stats,
    const float* __restrict__ g, const float* __restrict__ beta,
    float* __restrict__ out)
{
    __shared__ float t[32][33];
    const int b = blockIdx.z;
    const int n0 = blockIdx.x * 32, m0 = blockIdx.y * 32;   // n=d, m=s
    const int tx = threadIdx.x, ty = threadIdx.y;
    const u16* ip = in + (size_t)b * S_LEN * D_DIM;
    float* op = out + (size_t)b * S_LEN * D_DIM;
#pragma unroll
    for (int u = 0; u < 4; u++)
        t[ty + u * 8][tx] = bf2f(ip[(size_t)(m0 + ty + u * 8) * D_DIM + n0 + tx]);
    __syncthreads();
    const float2 st = stats[b * S_LEN + m0 + tx];
#pragma unroll
    for (int u = 0; u < 4; u++) {
        const int d = n0 + ty + u * 8;
        const float val = (t[tx][ty + u * 8] - st.x) * st.y * g[d] + beta[d];
        op[(size_t)d * S_LEN + m0 + tx] = val;
    }
}

// --------------------- forward real-FFT: 2048-pt via 1024-pt complex packing
// one block per (b,d) row of [B,D,S]; stores half-spectrum X[0..1023];
// accumulates count(mag^2 > 0.01*max^2) over all 2048 bins (conj symmetry).
__global__ __launch_bounds__(256) void fft_fwd(
    const float* __restrict__ in, float2* __restrict__ X, int* __restrict__ counts)
{
    __shared__ float re[1024], im[1024], twr[512], twi[512];
    __shared__ float redf[4];
    __shared__ int redi[4];
    const int tid = threadIdx.x;
    const int row = blockIdx.x;          // b*D + d
    const float2* src = (const float2*)(in + (size_t)row * S_LEN);
#pragma unroll
    for (int u = 0; u < 2; u++) {
        int j = tid + u * 256;
        float ang = -3.14159265358979f * (float)j * (1.0f / 512.0f);
        float sn, cs; __sincosf(ang, &sn, &cs);
        twr[j] = cs; twi[j] = sn;
    }
#pragma unroll
    for (int u = 0; u < 4; u++) {
        int t = tid + u * 256;
        float2 z = src[t];               // z[t] = x[2t] + i x[2t+1]
        int r = __brev((unsigned)t) >> 22;
        re[r] = z.x; im[r] = z.y;
    }
    __syncthreads();
    for (int st = 1; st <= 10; ++st) {
        const int mh = 1 << (st - 1);
#pragma unroll
        for (int u = 0; u < 2; u++) {
            int tb = tid + u * 256;
            int gidx = tb >> (st - 1);
            int j = tb & (mh - 1);
            int i1 = (gidx << st) + j;
            int i2 = i1 + mh;
            int ti = j << (10 - st);
            float wr = twr[ti], wi = twi[ti];
            float xr = re[i2], xi = im[i2];
            float vr = xr * wr - xi * wi;
            float vi = xr * wi + xi * wr;
            float ur = re[i1], ui = im[i1];
            re[i1] = ur + vr; im[i1] = ui + vi;
            re[i2] = ur - vr; im[i2] = ui - vi;
        }
        __syncthreads();
    }
    // post-process: X[k] = E[k] + w2^k O[k], k<1024; X[1024] = re0-im0
    float2* dst = X + (size_t)row * 1024;
    float mag[4];
    float xtra = 0.0f;
    float lmax = 0.0f;
#pragma unroll
    for (int u = 0; u < 4; u++) {
        int k = tid + u * 256;
        int mk = (1024 - k) & 1023;
        float rk = re[k], ik = im[k], rm = re[mk], imm = im[mk];
        float er = 0.5f * (rk + rm);
        float ei = 0.5f * (ik - imm);
        float orr = 0.5f * (ik + imm);          // O = 0.5*(di, -dr)
        float oii = -0.5f * (rk - rm);
        float ang = -3.14159265358979f * (float)k * (1.0f / 1024.0f);
        float sn, cs; __sincosf(ang, &sn, &cs);
        float xr = er + orr * cs - oii * sn;
        float xi = ei + orr * sn + oii * cs;
        dst[k] = make_float2(xr, xi);
        float m2 = xr * xr + xi * xi;
        mag[u] = m2;
        lmax = fmaxf(lmax, m2);
        if (k == 0) {
            float x1024 = re[0] - im[0];
            xtra = x1024 * x1024;
            lmax = fmaxf(lmax, xtra);
        }
    }
#pragma unroll
    for (int off = 32; off > 0; off >>= 1) lmax = fmaxf(lmax, __shfl_xor(lmax, off));
    if ((tid & 63) == 0) redf[tid >> 6] = lmax;
    __syncthreads();
    const float bmax = fmaxf(fmaxf(redf[0], redf[1]), fmaxf(redf[2], redf[3]));
    const float thr = 0.01f * bmax;
    int lc = 0;
#pragma unroll
    for (int u = 0; u < 4; u++) {
        int k = tid + u * 256;
        lc += (mag[u] > thr) ? ((k == 0) ? 1 : 2) : 0;
    }
    if (tid == 0) lc += (xtra > thr) ? 1 : 0;
#pragma unroll
    for (int off = 32; off > 0; off >>= 1) lc += __shfl_xor(lc, off);
    if ((tid & 63) == 0) redi[tid >> 6] = lc;
    __syncthreads();
    if (tid == 0)
        atomicAdd(&counts[(row >> 10) * 64 + (row & 63)],
                  redi[0] + redi[1] + redi[2] + redi[3]);
}

// ------------------------------------------------------------- N from counts
__global__ void calc_n(const int* __restrict__ counts, int* __restrict__ Ndev)
{
    const int t = threadIdx.x;           // 64 threads
    for (int b = 0; b < B_BATCH; b++) {
        int c = counts[b * 64 + t];
#pragma unroll
        for (int off = 32; off > 0; off >>= 1) c += __shfl_xor(c, off);
        if (t == 0) {
            float cf = (float)c * (1.0f / 2097152.0f);
            float cr = 0.5f * (1.0f - cf);
            cr = fminf(fmaxf(cr, 0.1f), 1.0f);
            int n = (int)(cr * 2048.0f);
            n = n < 1 ? 1 : (n > S_LEN ? S_LEN : n);
            Ndev[b] = n;
        }
    }
}

// --------------------- masked inverse: real-output 2048-ifft via 1024-pt
// u[t] = x[2t] + i x[2t+1] = 0.5*ifft1024( (A+B) + i*(A-B)*w2^k )
// A = Hs[k], B = Hs[k+1024] = conj(H[1024-k])/2 (mask k<Nb, Nb<=1023)
__global__ __launch_bounds__(256) void fft_inv(
    const float2* __restrict__ X, const int* __restrict__ Ndev,
    float* __restrict__ out)
{
    __shared__ float re[1024], im[1024], twr[512], twi[512];
    const int tid = threadIdx.x;
    const int row = blockIdx.x;          // b*D + d
    const int Nb = Ndev[row >> 10];
    const float2* src = X + (size_t)row * 1024;
#pragma unroll
    for (int u = 0; u < 2; u++) {
        int j = tid + u * 256;
        float ang = 3.14159265358979f * (float)j * (1.0f / 512.0f);
        float sn, cs; __sincosf(ang, &sn, &cs);
        twr[j] = cs; twi[j] = sn;
    }
#pragma unroll
    for (int u = 0; u < 4; u++) {
        int k = tid + u * 256;
        float Ar = 0.f, Ai = 0.f, Br = 0.f, Bi = 0.f;
        if (k == 0) {
            float2 h = src[0];           // (real, 0)
            Ar = h.x; Ai = h.y;
        } else {
            if (k < Nb) { float2 h = src[k]; Ar = 0.5f * h.x; Ai = 0.5f * h.y; }
            int km = 1024 - k;
            if (km < Nb) { float2 h = src[km]; Br = 0.5f * h.x; Bi = -0.5f * h.y; }
        }
        float ang = 3.14159265358979f * (float)k * (1.0f / 1024.0f);
        float sn, cs; __sincosf(ang, &sn, &cs);
        float drr = Ar - Br, dri = Ai - Bi;
        float Dr = drr * cs - dri * sn;
        float Di = drr * sn + dri * cs;
        float Cr = (Ar + Br) - Di;
        float Ci = (Ai + Bi) + Dr;
        int r = __brev((unsigned)k) >> 22;
        re[r] = Cr; im[r] = Ci;
    }
    __syncthreads();
    for (int st = 1; st <= 10; ++st) {
        const int mh = 1 << (st - 1);
#pragma unroll
        for (int u = 0; u < 2; u++) {
            int tb = tid + u * 256;
            int gidx = tb >> (st - 1);
            int j = tb & (mh - 1);
            int i1 = (gidx << st) + j;
            int i2 = i1 + mh;
            int ti = j << (10 - st);
            float wr = twr[ti], wi = twi[ti];
            float xr = re[i2], xi = im[i2];
            float vr = xr * wr - xi * wi;
            float vi = xr * wi + xi * wr;
            float ur = re[i1], ui = im[i1];
            re[i1] = ur + vr; im[i1] = ui + vi;
            re[i2] = ur - vr; im[i2] = ui - vi;
        }
        __syncthreads();
    }
    float2* dst = (float2*)(out + (size_t)row * S_LEN);
#pragma unroll
    for (int u = 0; u < 4; u++) {
        int t = tid + u * 256;
        dst[t] = make_float2(re[t] * (1.0f / 2048.0f), im[t] * (1.0f / 2048.0f));
    }
}

// ------------------------------------- transpose + f32->bf16  [B][M][N]->[B][N][M]
__global__ __launch_bounds__(256) void transposeMN_b(
    const float* __restrict__ in, u16* __restrict__ out, int M, int N)
{
    __shared__ float t[32][33];
    const int b = blockIdx.z;
    const int n0 = blockIdx.x * 32, m0 = blockIdx.y * 32;
    const int tx = threadIdx.x, ty = threadIdx.y;
    const float* ip = in + (size_t)b * M * N;
    u16* op = out + (size_t)b * M * N;
#pragma unroll
    for (int u = 0; u < 4; u++)
        t[ty + u * 8][tx] = ip[(size_t)(m0 + ty + u * 8) * N + n0 + tx];
    __syncthreads();
#pragma unroll
    for (int u = 0; u < 4; u++)
        op[(size_t)(n0 + ty + u * 8) * M + m0 + tx] = f2bf(t[tx][ty + u * 8]);
}

// ------------------------------------------- layernorm (f32 in, f32+bf16 out)
__global__ __launch_bounds__(256) void ln_f32(
    const float* __restrict__ in, const float* __restrict__ g,
    const float* __restrict__ beta, float* __restrict__ outF, u16* __restrict__ outB)
{
    const int row = blockIdx.x;
    const int tid = threadIdx.x;
    float4 v = ((const float4*)(in + (size_t)row * D_DIM))[tid];
    float s = v.x + v.y + v.z + v.w;
    float s2 = v.x * v.x + v.y * v.y + v.z * v.z + v.w * v.w;
#pragma unroll
    for (int off = 32; off > 0; off >>= 1) {
        s += __shfl_xor(s, off);
        s2 += __shfl_xor(s2, off);
    }
    __shared__ float red[8];
    if ((tid & 63) == 0) { red[(tid >> 6) * 2] = s; red[(tid >> 6) * 2 + 1] = s2; }
    __syncthreads();
    s = red[0] + red[2] + red[4] + red[6];
    s2 = red[1] + red[3] + red[5] + red[7];
    const float m = s * (1.0f / D_DIM);
    const float var = s2 * (1.0f / D_DIM) - m * m;
    const float rs = rsqrtf(var + 1e-5f);
    float4 gg = ((const float4*)g)[tid];
    float4 bb = ((const float4*)beta)[tid];
    float4 o;
    o.x = (v.x - m) * rs * gg.x + bb.x;
    o.y = (v.y - m) * rs * gg.y + bb.y;
    o.z = (v.z - m) * rs * gg.z + bb.z;
    o.w = (v.w - m) * rs * gg.w + bb.w;
    ((float4*)(outF + (size_t)row * D_DIM))[tid] = o;
    uint2 pb;
    pb.x = (u32)f2bf(o.x) | ((u32)f2bf(o.y) << 16);
    pb.y = (u32)f2bf(o.z) | ((u32)f2bf(o.w) << 16);
    ((uint2*)(outB + (size_t)row * D_DIM))[tid] = pb;
}

// ------------------------------------------------- per-row loss statistics
__global__ __launch_bounds__(256) void row_stats(
    const float* __restrict__ xifft, const float* __restrict__ recon,
    const float* __restrict__ Sxx, const float* __restrict__ Stt,
    const float* __restrict__ Sxt,
    float* __restrict__ rowA, float* __restrict__ rowB)
{
    const int row = blockIdx.x;
    const int tid = threadIdx.x;
    float4 x = ((const float4*)(xifft + (size_t)row * D_DIM))[tid];
    float4 r = ((const float4*)(recon + (size_t)row * D_DIM))[tid];
    float xx = x.x * x.x + x.y * x.y + x.z * x.z + x.w * x.w;
    float rr = r.x * r.x + r.y * r.y + r.z * r.z + r.w * r.w;
    float xr = x.x * r.x + x.y * r.y + x.z * r.z + x.w * r.w;
    float l1 = 0.f;
    {
        float d, ad;
        d = x.x - r.x; ad = fabsf(d); l1 += (ad < 1.0f) ? 0.5f * d * d : ad - 0.5f;
        d = x.y - r.y; ad = fabsf(d); l1 += (ad < 1.0f) ? 0.5f * d * d : ad - 0.5f;
        d = x.z - r.z; ad = fabsf(d); l1 += (ad < 1.0f) ? 0.5f * d * d : ad - 0.5f;
        d = x.w - r.w; ad = fabsf(d); l1 += (ad < 1.0f) ? 0.5f * d * d : ad - 0.5f;
    }
#pragma unroll
    for (int off = 32; off > 0; off >>= 1) {
        xx += __shfl_xor(xx, off); rr += __shfl_xor(rr, off);
        xr += __shfl_xor(xr, off); l1 += __shfl_xor(l1, off);
    }
    __shared__ float red[4][4];
    if ((tid & 63) == 0) {
        int w = tid >> 6;
        red[w][0] = xx; red[w][1] = rr; red[w][2] = xr; red[w][3] = l1;
    }
    __syncthreads();
    if (tid == 0) {
        xx = red[0][0] + red[1][0] + red[2][0] + red[3][0];
        rr = red[0][1] + red[1][1] + red[2][1] + red[3][1];
        xr = red[0][2] + red[1][2] + red[2][2] + red[3][2];
        l1 = red[0][3] + red[1][3] + red[2][3] + red[3][3];
        float nx = fmaxf(sqrtf(xx), 1e-12f);
        float nr = fmaxf(sqrtf(rr), 1e-12f);
        float cs = xr / (nx * nr);
        cs = fminf(fmaxf(cs, -1.0f + 1e-8f), 1.0f - 1e-8f);
        rowA[row] = 1.0f - cs;
        float sx = Sxx[row], st = Stt[row], sxtv = Sxt[row];
        float nxx = fmaxf(sqrtf(sx), 1e-12f);
        float ntt = fmaxf(sqrtf(st), 1e-12f);
        float sem = (sx / (nxx * nxx) + st / (ntt * ntt)
                     - 2.0f * sxtv / (nxx * ntt)) * (1.0f / D_DIM);
        rowB[row] = 0.2f * (l1 * (1.0f / D_DIM)) + 0.2f * sem;
    }
}

// ------------------------------------------------------------- final loss
__global__ __launch_bounds__(1024) void final_loss(
    const float* __restrict__ rowA, const float* __restrict__ rowB,
    const int* __restrict__ Ndev, float* __restrict__ out)
{
    const int tid = threadIdx.x;
    float sa = 0.f, sb = 0.f;
#pragma unroll
    for (int i = 0; i < 16; i++) {
        int r = tid + i * 1024;
        sa += rowA[r];
        int b = r >> 11, s = r & (S_LEN - 1);
        if (s < Ndev[b]) sb += rowB[r];
    }
#pragma unroll
    for (int off = 32; off > 0; off >>= 1) {
        sa += __shfl_xor(sa, off);
        sb += __shfl_xor(sb, off);
    }
    __shared__ float ra[16], rb[16];
    if ((tid & 63) == 0) { ra[tid >> 6] = sa; rb[tid >> 6] = sb; }
    __syncthreads();
    if (tid == 0) {
        float A = 0.f, Bs = 0.f;
#pragma unroll
        for (int i = 0; i < 16; i++) { A += ra[i]; Bs += rb[i]; }
        int K = 0;
        for (int b = 0; b < B_BATCH; b++) K += Ndev[b];
        float Kf = (float)K;
        float M = A * (1.0f / 16384.0f);
        out[(size_t)R_ROWS * D_DIM] = (0.6f * M * Kf + Bs) / (Kf + 1e-8f);
    }
}

// ---------------------------------------------------------------------------
extern "C" void kernel_launch(void* const* d_in, const int* in_sizes, int n_in,
                              void* d_out, int out_size, void* d_ws, size_t ws_size,
                              hipStream_t stream)
{
    (void)in_sizes; (void)n_in; (void)out_size; (void)ws_size;
    const int*   x       = (const int*)  d_in[0];
    const float* tok     = (const float*)d_in[1];
    const float* pos     = (const float*)d_in[2];
    const float* conv1_w = (const float*)d_in[3];
    const float* conv1_b = (const float*)d_in[4];
    const float* conv2_w = (const float*)d_in[5];
    const float* conv2_b = (const float*)d_in[6];
    const float* proj_w  = (const float*)d_in[7];
    const float* proj_b  = (const float*)d_in[8];
    const float* ph_w    = (const float*)d_in[9];
    const float* ph_b    = (const float*)d_in[10];
    const float* ln_g    = (const float*)d_in[11];
    const float* ln_b    = (const float*)d_in[12];
    float* out = (float*)d_out;

    char* ws = (char*)d_ws;
    int*    counts = (int*)(ws);                         // 512 ints
    int*    Ndev   = (int*)(ws + 2048);
    float2* stats  = (float2*)(ws + 4096);               // 128 KB -> 135168
    float*  Sxx    = (float*)(ws + 135168);
    float*  Stt    = (float*)(ws + 200704);
    float*  Sxt    = (float*)(ws + 266240);
    float*  rowA   = (float*)(ws + 331776);
    float*  rowB   = (float*)(ws + 397312);              // ends 462848
    const size_t MB = 1ull << 20;
    u16*   WT   = (u16*)(ws + 1 * MB);      // 16 MB (8 matrices of 1M bf16)
    u16*   P0   = (u16*)(ws + 17 * MB);     // 32.03 MB padded bf16 activations
    u16*   P1   = (u16*)(ws + 50 * MB);     // 32.03 MB
    float* F32A = (float*)(ws + 83 * MB);   // 64 MiB (also half-spectrum)
    float* F32B = (float*)(ws + 148 * MB);  // 64 MiB

    hipMemsetAsync(ws, 0, MB, stream);
    zero_pads<<<32, 256, 0, stream>>>(P0, P1);
    wconv<<<dim3(32, 32, 3), dim3(32, 8), 0, stream>>>(conv1_w, WT);
    wconv<<<dim3(32, 32, 3), dim3(32, 8), 0, stream>>>(conv2_w, WT + 3u * (1u << 20));
    wconv<<<dim3(32, 32, 1), dim3(32, 8), 0, stream>>>(proj_w, WT + 6u * (1u << 20));
    wconv<<<dim3(32, 32, 1), dim3(32, 8), 0, stream>>>(ph_w, WT + 7u * (1u << 20));
    // h0 (padded bf16)
    emb_kernel<<<R_ROWS, 256, 0, stream>>>(x, tok, pos, P0);
    // h1 = gelu(conv1(h0)) -> P1 padded
    gemm_mfma<<<dim3(8, 128), 256, 0, stream>>>(P0, WT, conv1_b, nullptr, P1,
        nullptr, nullptr, nullptr, nullptr, 3, 1, 1, 1);
    // h2 = gelu(conv2(h1)) -> P0 flat
    gemm_mfma<<<dim3(8, 128), 256, 0, stream>>>(P1, WT + 3u * (1u << 20), conv2_b, nullptr, P0,
        nullptr, nullptr, nullptr, nullptr, 3, 1, 1, 0);
    // LN stats + fused LN-transpose -> F32B [B,D,S]
    ln_stats<<<R_ROWS, 256, 0, stream>>>(P0, stats);
    transposeLN<<<dim3(32, 64, 8), dim3(32, 8), 0, stream>>>(P0, stats, ln_g, ln_b, F32B);
    // forward FFT (half-spectrum into F32A) + complexity counts
    fft_fwd<<<BD_ROWS, 256, 0, stream>>>(F32B, (float2*)F32A, counts);
    calc_n<<<1, 64, 0, stream>>>(counts, Ndev);
    // masked inverse FFT -> F32B [B,D,S]
    fft_inv<<<BD_ROWS, 256, 0, stream>>>((const float2*)F32A, Ndev, F32B);
    // [B,D,S] -> [B,S,D] bf16 -> P0 flat
    transposeMN_b<<<dim3(64, 32, 8), dim3(32, 8), 0, stream>>>(F32B, P0, D_DIM, S_LEN);
    // proj_out = x_ifft_raw @ proj_w + b -> F32A (recon f32) + P1 (bf16)
    gemm_mfma<<<dim3(8, 128), 256, 0, stream>>>(P0, WT + 6u * (1u << 20), proj_b, F32A, P1,
        nullptr, nullptr, nullptr, nullptr, 1, 0, 0, 0);
    // x_ifft = LN(proj_out) -> d_out (f32) + P0 (bf16)
    ln_f32<<<R_ROWS, 256, 0, stream>>>(F32A, ln_g, ln_b, out, P0);
    // pt = recon @ ph_w + b -> F32B
    gemm_mfma<<<dim3(8, 128), 256, 0, stream>>>(P1, WT + 7u * (1u << 20), ph_b, F32B, nullptr,
        nullptr, nullptr, nullptr, nullptr, 1, 0, 0, 0);
    // px = x_ifft @ ph_w + b; fused row stats vs pt
    gemm_mfma<<<dim3(8, 128), 256, 0, stream>>>(P0, WT + 7u * (1u << 20), ph_b, nullptr, nullptr,
        F32B, Sxx, Stt, Sxt, 1, 0, 0, 0);
    // per-row loss stats (no atomics) + final reduce
    row_stats<<<R_ROWS, 256, 0, stream>>>(out, F32A, Sxx, Stt, Sxt, rowA, rowB);
    final_loss<<<1, 1024, 0, stream>>>(rowA, rowB, Ndev, out);
}

// Round 4
// 742.390 us; speedup vs baseline: 5.6408x; 1.0241x over previous
//
#include <hip/hip_runtime.h>
#include <math.h>

#define S_LEN 2048
#define D_DIM 1024
#define B_BATCH 8
#define R_ROWS (B_BATCH * S_LEN)    // 16384
#define BD_ROWS (B_BATCH * D_DIM)   // 8192
#define PAD_ROWS 2050               // 1 zero row + 2048 + 1 zero row per batch

typedef unsigned short u16;
typedef unsigned int u32;
typedef __attribute__((ext_vector_type(8))) short bf16x8;
typedef __attribute__((ext_vector_type(4))) float f32x4;

__device__ __forceinline__ u16 f2bf(float f) {
    u32 x = __float_as_uint(f);
    u32 r = (x + 0x7fffu + ((x >> 16) & 1u)) >> 16;   // RNE
    return (u16)r;
}
__device__ __forceinline__ float bf2f(u16 u) {
    return __uint_as_float(((u32)u) << 16);
}
__device__ __forceinline__ float gelu_exact(float x) {
    return 0.5f * x * (1.0f + erff(x * 0.70710678118654752f));
}

#define GLDS(gsrc, ldst)                                                                   \
    __builtin_amdgcn_global_load_lds(                                                      \
        (const __attribute__((address_space(1))) u32*)(gsrc),                              \
        (__attribute__((address_space(3))) u32*)(ldst), 16, 0, 0)

// XCD-locality swizzle for grid (8 cols x 128 rows): each XCD owns a
// contiguous 16-row-panel range (4MB of A = one XCD L2).
__device__ __forceinline__ void swz_blocks(int& bx, int& by) {
    const int flat = blockIdx.y * 8 + blockIdx.x;
    const int xcd = flat & 7;
    const int i = flat >> 3;            // 0..127
    by = xcd * 16 + (i >> 3);
    bx = i & 7;
}

// ----------------------------------------------------------- zero pad rows
__global__ __launch_bounds__(256) void zero_pads(u16* __restrict__ P0, u16* __restrict__ P1)
{
    const int bid = blockIdx.x;          // 0..31
    u16* P = (bid >= 16) ? P1 : P0;
    const int ridx = bid & 15;
    const int b = ridx >> 1;
    const size_t row = (size_t)b * PAD_ROWS + (size_t)(ridx & 1) * (PAD_ROWS - 1);
    ((uint2*)(P + row * D_DIM))[threadIdx.x] = make_uint2(0u, 0u);
}

// ----------------------------------------- weight convert+transpose to bf16
// in: W f32 [T][K=1024][N=1024]; out: WT bf16 [T][N][K]
__global__ __launch_bounds__(256) void wconv(const float* __restrict__ W, u16* __restrict__ WT)
{
    __shared__ float t[32][33];
    const int tap = blockIdx.z;
    const int n0 = blockIdx.x * 32, k0 = blockIdx.y * 32;
    const int tx = threadIdx.x, ty = threadIdx.y;
    const float* ip = W + (size_t)tap * D_DIM * D_DIM;
    u16* op = WT + (size_t)tap * D_DIM * D_DIM;
#pragma unroll
    for (int u = 0; u < 4; u++)
        t[ty + u * 8][tx] = ip[(size_t)(k0 + ty + u * 8) * D_DIM + n0 + tx];
    __syncthreads();
#pragma unroll
    for (int u = 0; u < 4; u++)
        op[(size_t)(n0 + ty + u * 8) * D_DIM + k0 + tx] = f2bf(t[tx][ty + u * 8]);
}

// ---------------------------------------------------------------- embedding
__global__ __launch_bounds__(256) void emb_kernel(
    const int* __restrict__ x, const float* __restrict__ tok,
    const float* __restrict__ pos, u16* __restrict__ P0)
{
    const int row = blockIdx.x;          // b*S + s
    const int tid = threadIdx.x;
    const int t = x[row];
    const int s = row & (S_LEN - 1);
    const int b = row >> 11;
    float4 a = ((const float4*)(tok + (size_t)t * D_DIM))[tid];
    float4 p = ((const float4*)(pos + (size_t)s * D_DIM))[tid];
    uint2 v;
    v.x = (u32)f2bf(a.x + p.x) | ((u32)f2bf(a.y + p.y) << 16);
    v.y = (u32)f2bf(a.z + p.z) | ((u32)f2bf(a.w + p.w) << 16);
    ((uint2*)(P0 + ((size_t)b * PAD_ROWS + 1 + s) * D_DIM))[tid] = v;
}

// ------------------------------------------------------- bf16 MFMA GEMM/conv
__global__ __launch_bounds__(256, 2) void gemm_mfma(
    const u16* __restrict__ A, const u16* __restrict__ WT,
    const float* __restrict__ bias,
    float* __restrict__ outF, u16* __restrict__ outB,
    int ntaps, int doGelu, int aPadded, int outBPadded)
{
    __shared__ u16 Abuf[128 * 32];
    __shared__ u16 Bbuf[128 * 32];
    const int tid = threadIdx.x;
    const int wid = tid >> 6, lane = tid & 63;
    const int wr = wid >> 1, wc = wid & 1;
    int bx, by;
    swz_blocks(bx, by);
    const int col0 = bx * 128;
    const int row0 = by * 128;
    const int b = row0 >> 11;
    const int srow0 = row0 & (S_LEN - 1);
    const int l15 = lane & 15, l4 = lane >> 4;

    f32x4 acc[4][4];
#pragma unroll
    for (int i = 0; i < 4; i++)
#pragma unroll
        for (int j = 0; j < 4; j++) acc[i][j] = (f32x4){0.f, 0.f, 0.f, 0.f};

    for (int tap = 0; tap < ntaps; ++tap) {
        const size_t aBase = aPadded ? ((size_t)(b * PAD_ROWS + srow0 + tap) << 10)
                                     : ((size_t)row0 << 10);
        const u16* Wt = WT + ((size_t)tap << 20) + ((size_t)col0 << 10);
        for (int k0 = 0; k0 < D_DIM; k0 += 32) {
#pragma unroll
            for (int c = 0; c < 2; c++) {
                const int chunk = wid + c * 4;
                const int off = chunk * 1024 + lane * 16;   // byte offset in 8KB tile
                const int r = off >> 6;
                const int cb = off & 63;
                GLDS(A + aBase + ((size_t)r << 10) + (size_t)(k0 + (cb >> 1)),
                     (char*)Abuf + off);
                GLDS(Wt + ((size_t)r << 10) + (size_t)(k0 + (cb >> 1)),
                     (char*)Bbuf + off);
            }
            __syncthreads();
            bf16x8 af[4], bfr[4];
#pragma unroll
            for (int mi = 0; mi < 4; mi++)
                af[mi] = *(const bf16x8*)&Abuf[(wr * 64 + mi * 16 + l15) * 32 + l4 * 8];
#pragma unroll
            for (int ni = 0; ni < 4; ni++)
                bfr[ni] = *(const bf16x8*)&Bbuf[(wc * 64 + ni * 16 + l15) * 32 + l4 * 8];
#pragma unroll
            for (int mi = 0; mi < 4; mi++)
#pragma unroll
                for (int ni = 0; ni < 4; ni++)
                    acc[mi][ni] = __builtin_amdgcn_mfma_f32_16x16x32_bf16(
                        af[mi], bfr[ni], acc[mi][ni], 0, 0, 0);
            __syncthreads();
        }
    }

    float bv[4];
#pragma unroll
    for (int ni = 0; ni < 4; ni++) bv[ni] = bias[col0 + wc * 64 + ni * 16 + l15];

#pragma unroll
    for (int mi = 0; mi < 4; mi++) {
#pragma unroll
        for (int ni = 0; ni < 4; ni++) {
#pragma unroll
            for (int reg = 0; reg < 4; reg++) {
                const int row = row0 + wr * 64 + mi * 16 + l4 * 4 + reg;
                const int col = col0 + wc * 64 + ni * 16 + l15;
                float v = acc[mi][ni][reg] + bv[ni];
                if (doGelu) v = gelu_exact(v);
                if (outF) outF[(size_t)row * D_DIM + col] = v;
                if (outB) {
                    const size_t orow = outBPadded
                        ? ((size_t)(row >> 11) * PAD_ROWS + 1 + (size_t)(row & (S_LEN - 1)))
                        : (size_t)row;
                    outB[orow * D_DIM + col] = f2bf(v);
                }
            }
        }
    }
}

// ---------------- fused ph-projection stats: px=X@W+b, pt=R@W+b in one pass
__global__ __launch_bounds__(256) void phstats_mfma(
    const u16* __restrict__ X, const u16* __restrict__ R,
    const u16* __restrict__ WT, const float* __restrict__ bias,
    float* __restrict__ Sxx, float* __restrict__ Stt, float* __restrict__ Sxt)
{
    __shared__ u16 Xbuf[128 * 32];
    __shared__ u16 Rbuf[128 * 32];
    __shared__ u16 Bbuf[128 * 32];
    const int tid = threadIdx.x;
    const int wid = tid >> 6, lane = tid & 63;
    const int wr = wid >> 1, wc = wid & 1;
    int bx, by;
    swz_blocks(bx, by);
    const int col0 = bx * 128;
    const int row0 = by * 128;
    const int l15 = lane & 15, l4 = lane >> 4;

    f32x4 accx[4][4], accr[4][4];
#pragma unroll
    for (int i = 0; i < 4; i++)
#pragma unroll
        for (int j = 0; j < 4; j++) {
            accx[i][j] = (f32x4){0.f, 0.f, 0.f, 0.f};
            accr[i][j] = (f32x4){0.f, 0.f, 0.f, 0.f};
        }

    const u16* Wt = WT + ((size_t)col0 << 10);
    for (int k0 = 0; k0 < D_DIM; k0 += 32) {
#pragma unroll
        for (int c = 0; c < 2; c++) {
            const int chunk = wid + c * 4;
            const int off = chunk * 1024 + lane * 16;
            const int r = off >> 6;
            const int cb = off & 63;
            const size_t goff = ((size_t)(row0 + r) << 10) + (size_t)(k0 + (cb >> 1));
            GLDS(X + goff, (char*)Xbuf + off);
            GLDS(R + goff, (char*)Rbuf + off);
            GLDS(Wt + ((size_t)r << 10) + (size_t)(k0 + (cb >> 1)), (char*)Bbuf + off);
        }
        __syncthreads();
        bf16x8 xf[4], rf[4], bfr[4];
#pragma unroll
        for (int mi = 0; mi < 4; mi++) {
            xf[mi] = *(const bf16x8*)&Xbuf[(wr * 64 + mi * 16 + l15) * 32 + l4 * 8];
            rf[mi] = *(const bf16x8*)&Rbuf[(wr * 64 + mi * 16 + l15) * 32 + l4 * 8];
        }
#pragma unroll
        for (int ni = 0; ni < 4; ni++)
            bfr[ni] = *(const bf16x8*)&Bbuf[(wc * 64 + ni * 16 + l15) * 32 + l4 * 8];
#pragma unroll
        for (int mi = 0; mi < 4; mi++)
#pragma unroll
            for (int ni = 0; ni < 4; ni++) {
                accx[mi][ni] = __builtin_amdgcn_mfma_f32_16x16x32_bf16(
                    xf[mi], bfr[ni], accx[mi][ni], 0, 0, 0);
                accr[mi][ni] = __builtin_amdgcn_mfma_f32_16x16x32_bf16(
                    rf[mi], bfr[ni], accr[mi][ni], 0, 0, 0);
            }
        __syncthreads();
    }

    float bv[4];
#pragma unroll
    for (int ni = 0; ni < 4; ni++) bv[ni] = bias[col0 + wc * 64 + ni * 16 + l15];

#pragma unroll
    for (int mi = 0; mi < 4; mi++) {
#pragma unroll
        for (int reg = 0; reg < 4; reg++) {
            const int row = row0 + wr * 64 + mi * 16 + l4 * 4 + reg;
            float sxx = 0.f, stt = 0.f, sxt = 0.f;
#pragma unroll
            for (int ni = 0; ni < 4; ni++) {
                float px = accx[mi][ni][reg] + bv[ni];
                float pt = accr[mi][ni][reg] + bv[ni];
                sxx = fmaf(px, px, sxx);
                stt = fmaf(pt, pt, stt);
                sxt = fmaf(px, pt, sxt);
            }
#pragma unroll
            for (int off = 1; off < 16; off <<= 1) {
                sxx += __shfl_xor(sxx, off);
                stt += __shfl_xor(stt, off);
                sxt += __shfl_xor(sxt, off);
            }
            if (l15 == 0) {
                atomicAdd(&Sxx[row], sxx);
                atomicAdd(&Stt[row], stt);
                atomicAdd(&Sxt[row], sxt);
            }
        }
    }
}

// ------------------------------------------- per-row LN stats (mean, rstd)
__global__ __launch_bounds__(256) void ln_stats(
    const u16* __restrict__ in, float2* __restrict__ stats)
{
    const int row = blockIdx.x;
    const int tid = threadIdx.x;
    uint2 raw = ((const uint2*)(in + (size_t)row * D_DIM))[tid];
    float v0 = bf2f((u16)(raw.x & 0xffff)), v1 = bf2f((u16)(raw.x >> 16));
    float v2 = bf2f((u16)(raw.y & 0xffff)), v3 = bf2f((u16)(raw.y >> 16));
    float s = v0 + v1 + v2 + v3;
    float s2 = v0 * v0 + v1 * v1 + v2 * v2 + v3 * v3;
#pragma unroll
    for (int off = 32; off > 0; off >>= 1) {
        s += __shfl_xor(s, off);
        s2 += __shfl_xor(s2, off);
    }
    __shared__ float red[8];
    if ((tid & 63) == 0) { red[(tid >> 6) * 2] = s; red[(tid >> 6) * 2 + 1] = s2; }
    __syncthreads();
    if (tid == 0) {
        s = red[0] + red[2] + red[4] + red[6];
        s2 = red[1] + red[3] + red[5] + red[7];
        const float m = s * (1.0f / D_DIM);
        const float var = s2 * (1.0f / D_DIM) - m * m;
        stats[row] = make_float2(m, rsqrtf(var + 1e-5f));
    }
}

// ------------------- fused LN + transpose: bf16 [B,S,D] -> f32 [B,D,S]
__global__ __launch_bounds__(256) void transposeLN(
    const u16* __restrict__ in, const float2* __restrict__ stats,
    const float* __restrict__ g, const float* __restrict__ beta,
    float* __restrict__ out)
{
    __shared__ float t[32][33];
    const int b = blockIdx.z;
    const int n0 = blockIdx.x * 32, m0 = blockIdx.y * 32;   // n=d, m=s
    const int tx = threadIdx.x, ty = threadIdx.y;
    const u16* ip = in + (size_t)b * S_LEN * D_DIM;
    float* op = out + (size_t)b * S_LEN * D_DIM;
#pragma unroll
    for (int u = 0; u < 4; u++)
        t[ty + u * 8][tx] = bf2f(ip[(size_t)(m0 + ty + u * 8) * D_DIM + n0 + tx]);
    __syncthreads();
    const float2 st = stats[b * S_LEN + m0 + tx];
#pragma unroll
    for (int u = 0; u < 4; u++) {
        const int d = n0 + ty + u * 8;
        const float val = (t[tx][ty + u * 8] - st.x) * st.y * g[d] + beta[d];
        op[(size_t)d * S_LEN + m0 + tx] = val;
    }
}

// --------------------- forward real-FFT: 2048-pt via 1024-pt complex packing
__global__ __launch_bounds__(256) void fft_fwd(
    const float* __restrict__ in, float2* __restrict__ X, int* __restrict__ counts)
{
    __shared__ float re[1024], im[1024], twr[512], twi[512];
    __shared__ float redf[4];
    __shared__ int redi[4];
    const int tid = threadIdx.x;
    const int row = blockIdx.x;          // b*D + d
    const float2* src = (const float2*)(in + (size_t)row * S_LEN);
#pragma unroll
    for (int u = 0; u < 2; u++) {
        int j = tid + u * 256;
        float ang = -3.14159265358979f * (float)j * (1.0f / 512.0f);
        float sn, cs; __sincosf(ang, &sn, &cs);
        twr[j] = cs; twi[j] = sn;
    }
#pragma unroll
    for (int u = 0; u < 4; u++) {
        int t = tid + u * 256;
        float2 z = src[t];               // z[t] = x[2t] + i x[2t+1]
        int r = __brev((unsigned)t) >> 22;
        re[r] = z.x; im[r] = z.y;
    }
    __syncthreads();
    for (int st = 1; st <= 10; ++st) {
        const int mh = 1 << (st - 1);
#pragma unroll
        for (int u = 0; u < 2; u++) {
            int tb = tid + u * 256;
            int gidx = tb >> (st - 1);
            int j = tb & (mh - 1);
            int i1 = (gidx << st) + j;
            int i2 = i1 + mh;
            int ti = j << (10 - st);
            float wr = twr[ti], wi = twi[ti];
            float xr = re[i2], xi = im[i2];
            float vr = xr * wr - xi * wi;
            float vi = xr * wi + xi * wr;
            float ur = re[i1], ui = im[i1];
            re[i1] = ur + vr; im[i1] = ui + vi;
            re[i2] = ur - vr; im[i2] = ui - vi;
        }
        __syncthreads();
    }
    float2* dst = X + (size_t)row * 1024;
    float mag[4];
    float xtra = 0.0f;
    float lmax = 0.0f;
#pragma unroll
    for (int u = 0; u < 4; u++) {
        int k = tid + u * 256;
        int mk = (1024 - k) & 1023;
        float rk = re[k], ik = im[k], rm = re[mk], imm = im[mk];
        float er = 0.5f * (rk + rm);
        float ei = 0.5f * (ik - imm);
        float orr = 0.5f * (ik + imm);
        float oii = -0.5f * (rk - rm);
        float ang = -3.14159265358979f * (float)k * (1.0f / 1024.0f);
        float sn, cs; __sincosf(ang, &sn, &cs);
        float xr = er + orr * cs - oii * sn;
        float xi = ei + orr * sn + oii * cs;
        dst[k] = make_float2(xr, xi);
        float m2 = xr * xr + xi * xi;
        mag[u] = m2;
        lmax = fmaxf(lmax, m2);
        if (k == 0) {
            float x1024 = re[0] - im[0];
            xtra = x1024 * x1024;
            lmax = fmaxf(lmax, xtra);
        }
    }
#pragma unroll
    for (int off = 32; off > 0; off >>= 1) lmax = fmaxf(lmax, __shfl_xor(lmax, off));
    if ((tid & 63) == 0) redf[tid >> 6] = lmax;
    __syncthreads();
    const float bmax = fmaxf(fmaxf(redf[0], redf[1]), fmaxf(redf[2], redf[3]));
    const float thr = 0.01f * bmax;
    int lc = 0;
#pragma unroll
    for (int u = 0; u < 4; u++) {
        int k = tid + u * 256;
        lc += (mag[u] > thr) ? ((k == 0) ? 1 : 2) : 0;
    }
    if (tid == 0) lc += (xtra > thr) ? 1 : 0;
#pragma unroll
    for (int off = 32; off > 0; off >>= 1) lc += __shfl_xor(lc, off);
    if ((tid & 63) == 0) redi[tid >> 6] = lc;
    __syncthreads();
    if (tid == 0)
        atomicAdd(&counts[(row >> 10) * 64 + (row & 63)],
                  redi[0] + redi[1] + redi[2] + redi[3]);
}

// ------------------------------------------------------------- N from counts
__global__ void calc_n(const int* __restrict__ counts, int* __restrict__ Ndev)
{
    const int t = threadIdx.x;           // 64 threads
    for (int b = 0; b < B_BATCH; b++) {
        int c = counts[b * 64 + t];
#pragma unroll
        for (int off = 32; off > 0; off >>= 1) c += __shfl_xor(c, off);
        if (t == 0) {
            float cf = (float)c * (1.0f / 2097152.0f);
            float cr = 0.5f * (1.0f - cf);
            cr = fminf(fmaxf(cr, 0.1f), 1.0f);
            int n = (int)(cr * 2048.0f);
            n = n < 1 ? 1 : (n > S_LEN ? S_LEN : n);
            Ndev[b] = n;
        }
    }
}

// --------------------- masked inverse 2048-ifft (real part) -> bf16 [B,D,S]
__global__ __launch_bounds__(256) void fft_inv(
    const float2* __restrict__ X, const int* __restrict__ Ndev,
    u16* __restrict__ outb)
{
    __shared__ float re[1024], im[1024], twr[512], twi[512];
    const int tid = threadIdx.x;
    const int row = blockIdx.x;          // b*D + d
    const int Nb = Ndev[row >> 10];
    const float2* src = X + (size_t)row * 1024;
#pragma unroll
    for (int u = 0; u < 2; u++) {
        int j = tid + u * 256;
        float ang = 3.14159265358979f * (float)j * (1.0f / 512.0f);
        float sn, cs; __sincosf(ang, &sn, &cs);
        twr[j] = cs; twi[j] = sn;
    }
#pragma unroll
    for (int u = 0; u < 4; u++) {
        int k = tid + u * 256;
        float Ar = 0.f, Ai = 0.f, Br = 0.f, Bi = 0.f;
        if (k == 0) {
            float2 h = src[0];
            Ar = h.x; Ai = h.y;
        } else {
            if (k < Nb) { float2 h = src[k]; Ar = 0.5f * h.x; Ai = 0.5f * h.y; }
            int km = 1024 - k;
            if (km < Nb) { float2 h = src[km]; Br = 0.5f * h.x; Bi = -0.5f * h.y; }
        }
        float ang = 3.14159265358979f * (float)k * (1.0f / 1024.0f);
        float sn, cs; __sincosf(ang, &sn, &cs);
        float drr = Ar - Br, dri = Ai - Bi;
        float Dr = drr * cs - dri * sn;
        float Di = drr * sn + dri * cs;
        float Cr = (Ar + Br) - Di;
        float Ci = (Ai + Bi) + Dr;
        int r = __brev((unsigned)k) >> 22;
        re[r] = Cr; im[r] = Ci;
    }
    __syncthreads();
    for (int st = 1; st <= 10; ++st) {
        const int mh = 1 << (st - 1);
#pragma unroll
        for (int u = 0; u < 2; u++) {
            int tb = tid + u * 256;
            int gidx = tb >> (st - 1);
            int j = tb & (mh - 1);
            int i1 = (gidx << st) + j;
            int i2 = i1 + mh;
            int ti = j << (10 - st);
            float wr = twr[ti], wi = twi[ti];
            float xr = re[i2], xi = im[i2];
            float vr = xr * wr - xi * wi;
            float vi = xr * wi + xi * wr;
            float ur = re[i1], ui = im[i1];
            re[i1] = ur + vr; im[i1] = ui + vi;
            re[i2] = ur - vr; im[i2] = ui - vi;
        }
        __syncthreads();
    }
    u32* dst = (u32*)(outb + (size_t)row * S_LEN);
#pragma unroll
    for (int u = 0; u < 4; u++) {
        int t = tid + u * 256;
        u16 lo = f2bf(re[t] * (1.0f / 2048.0f));
        u16 hi = f2bf(im[t] * (1.0f / 2048.0f));
        dst[t] = (u32)lo | ((u32)hi << 16);
    }
}

// ---------------------- bf16 transpose [B][M][N] -> [B][N][M]
__global__ __launch_bounds__(256) void transpose_bb(
    const u16* __restrict__ in, u16* __restrict__ out, int M, int N)
{
    __shared__ u16 t[32][33];
    const int b = blockIdx.z;
    const int n0 = blockIdx.x * 32, m0 = blockIdx.y * 32;
    const int tx = threadIdx.x, ty = threadIdx.y;
    const u16* ip = in + (size_t)b * M * N;
    u16* op = out + (size_t)b * M * N;
#pragma unroll
    for (int u = 0; u < 4; u++)
        t[ty + u * 8][tx] = ip[(size_t)(m0 + ty + u * 8) * N + n0 + tx];
    __syncthreads();
#pragma unroll
    for (int u = 0; u < 4; u++)
        op[(size_t)(n0 + ty + u * 8) * M + m0 + tx] = t[tx][ty + u * 8];
}

// ----------- LN(proj_out) + cos-sim/smooth-L1 row stats, f32+bf16 outputs
__global__ __launch_bounds__(256) void ln_loss(
    const float* __restrict__ in, const float* __restrict__ g,
    const float* __restrict__ beta, float* __restrict__ outF, u16* __restrict__ outB,
    float* __restrict__ rowA, float* __restrict__ rowL1)
{
    const int row = blockIdx.x;
    const int tid = threadIdx.x;
    float4 v = ((const float4*)(in + (size_t)row * D_DIM))[tid];
    float s = v.x + v.y + v.z + v.w;
    float s2 = v.x * v.x + v.y * v.y + v.z * v.z + v.w * v.w;
#pragma unroll
    for (int off = 32; off > 0; off >>= 1) {
        s += __shfl_xor(s, off);
        s2 += __shfl_xor(s2, off);
    }
    __shared__ float red[8];
    if ((tid & 63) == 0) { red[(tid >> 6) * 2] = s; red[(tid >> 6) * 2 + 1] = s2; }
    __syncthreads();
    s = red[0] + red[2] + red[4] + red[6];
    s2 = red[1] + red[3] + red[5] + red[7];
    const float m = s * (1.0f / D_DIM);
    const float var = s2 * (1.0f / D_DIM) - m * m;
    const float rs = rsqrtf(var + 1e-5f);
    float4 gg = ((const float4*)g)[tid];
    float4 bb = ((const float4*)beta)[tid];
    float4 o;
    o.x = (v.x - m) * rs * gg.x + bb.x;
    o.y = (v.y - m) * rs * gg.y + bb.y;
    o.z = (v.z - m) * rs * gg.z + bb.z;
    o.w = (v.w - m) * rs * gg.w + bb.w;
    ((float4*)(outF + (size_t)row * D_DIM))[tid] = o;
    uint2 pb;
    pb.x = (u32)f2bf(o.x) | ((u32)f2bf(o.y) << 16);
    pb.y = (u32)f2bf(o.z) | ((u32)f2bf(o.w) << 16);
    ((uint2*)(outB + (size_t)row * D_DIM))[tid] = pb;

    // loss row stats: x = o (x_ifft), r = v (recon_target = proj_out)
    float xx = o.x * o.x + o.y * o.y + o.z * o.z + o.w * o.w;
    float rr = v.x * v.x + v.y * v.y + v.z * v.z + v.w * v.w;
    float xr = o.x * v.x + o.y * v.y + o.z * v.z + o.w * v.w;
    float l1 = 0.f;
    {
        float d, ad;
        d = o.x - v.x; ad = fabsf(d); l1 += (ad < 1.0f) ? 0.5f * d * d : ad - 0.5f;
        d = o.y - v.y; ad = fabsf(d); l1 += (ad < 1.0f) ? 0.5f * d * d : ad - 0.5f;
        d = o.z - v.z; ad = fabsf(d); l1 += (ad < 1.0f) ? 0.5f * d * d : ad - 0.5f;
        d = o.w - v.w; ad = fabsf(d); l1 += (ad < 1.0f) ? 0.5f * d * d : ad - 0.5f;
    }
#pragma unroll
    for (int off = 32; off > 0; off >>= 1) {
        xx += __shfl_xor(xx, off); rr += __shfl_xor(rr, off);
        xr += __shfl_xor(xr, off); l1 += __shfl_xor(l1, off);
    }
    __shared__ float red2[4][4];
    __syncthreads();
    if ((tid & 63) == 0) {
        int w = tid >> 6;
        red2[w][0] = xx; red2[w][1] = rr; red2[w][2] = xr; red2[w][3] = l1;
    }
    __syncthreads();
    if (tid == 0) {
        xx = red2[0][0] + red2[1][0] + red2[2][0] + red2[3][0];
        rr = red2[0][1] + red2[1][1] + red2[2][1] + red2[3][1];
        xr = red2[0][2] + red2[1][2] + red2[2][2] + red2[3][2];
        l1 = red2[0][3] + red2[1][3] + red2[2][3] + red2[3][3];
        float nx = fmaxf(sqrtf(xx), 1e-12f);
        float nr = fmaxf(sqrtf(rr), 1e-12f);
        float cs = xr / (nx * nr);
        cs = fminf(fmaxf(cs, -1.0f + 1e-8f), 1.0f - 1e-8f);
        rowA[row] = 1.0f - cs;
        rowL1[row] = l1;
    }
}

// ------------------------------------------------------------- final loss
__global__ __launch_bounds__(1024) void final_loss(
    const float* __restrict__ rowA, const float* __restrict__ rowL1,
    const float* __restrict__ Sxx, const float* __restrict__ Stt,
    const float* __restrict__ Sxt,
    const int* __restrict__ Ndev, float* __restrict__ out)
{
    const int tid = threadIdx.x;
    float sa = 0.f, sb = 0.f;
#pragma unroll
    for (int i = 0; i < 16; i++) {
        int r = tid + i * 1024;
        sa += rowA[r];
        int b = r >> 11, s = r & (S_LEN - 1);
        if (s < Ndev[b]) {
            float sx = Sxx[r], st = Stt[r], sxtv = Sxt[r];
            float nxx = fmaxf(sqrtf(sx), 1e-12f);
            float ntt = fmaxf(sqrtf(st), 1e-12f);
            float sem = (sx / (nxx * nxx) + st / (ntt * ntt)
                         - 2.0f * sxtv / (nxx * ntt)) * (1.0f / D_DIM);
            sb += 0.2f * (rowL1[r] * (1.0f / D_DIM)) + 0.2f * sem;
        }
    }
#pragma unroll
    for (int off = 32; off > 0; off >>= 1) {
        sa += __shfl_xor(sa, off);
        sb += __shfl_xor(sb, off);
    }
    __shared__ float ra[16], rb[16];
    if ((tid & 63) == 0) { ra[tid >> 6] = sa; rb[tid >> 6] = sb; }
    __syncthreads();
    if (tid == 0) {
        float A = 0.f, Bs = 0.f;
#pragma unroll
        for (int i = 0; i < 16; i++) { A += ra[i]; Bs += rb[i]; }
        int K = 0;
        for (int b = 0; b < B_BATCH; b++) K += Ndev[b];
        float Kf = (float)K;
        float M = A * (1.0f / 16384.0f);
        out[(size_t)R_ROWS * D_DIM] = (0.6f * M * Kf + Bs) / (Kf + 1e-8f);
    }
}

// ---------------------------------------------------------------------------
extern "C" void kernel_launch(void* const* d_in, const int* in_sizes, int n_in,
                              void* d_out, int out_size, void* d_ws, size_t ws_size,
                              hipStream_t stream)
{
    (void)in_sizes; (void)n_in; (void)out_size; (void)ws_size;
    const int*   x       = (const int*)  d_in[0];
    const float* tok     = (const float*)d_in[1];
    const float* pos     = (const float*)d_in[2];
    const float* conv1_w = (const float*)d_in[3];
    const float* conv1_b = (const float*)d_in[4];
    const float* conv2_w = (const float*)d_in[5];
    const float* conv2_b = (const float*)d_in[6];
    const float* proj_w  = (const float*)d_in[7];
    const float* proj_b  = (const float*)d_in[8];
    const float* ph_w    = (const float*)d_in[9];
    const float* ph_b    = (const float*)d_in[10];
    const float* ln_g    = (const float*)d_in[11];
    const float* ln_b    = (const float*)d_in[12];
    float* out = (float*)d_out;

    char* ws = (char*)d_ws;
    int*    counts = (int*)(ws);                         // 512 ints
    int*    Ndev   = (int*)(ws + 2048);
    float2* stats  = (float2*)(ws + 4096);               // 128 KB
    float*  Sxx    = (float*)(ws + 135168);
    float*  Stt    = (float*)(ws + 200704);
    float*  Sxt    = (float*)(ws + 266240);
    float*  rowA   = (float*)(ws + 331776);
    float*  rowL1  = (float*)(ws + 397312);              // ends 462848
    const size_t MB = 1ull << 20;
    u16*   WT   = (u16*)(ws + 1 * MB);      // 16 MB (8 matrices of 1M bf16)
    u16*   P0   = (u16*)(ws + 17 * MB);     // 32.05 MB padded bf16 activations
    u16*   P1   = (u16*)(ws + 50 * MB);     // 32.05 MB
    float* F32A = (float*)(ws + 83 * MB);   // 64 MiB (spectrum, then recon f32)
    float* F32B = (float*)(ws + 148 * MB);  // 64 MiB (LN'd [B,D,S] f32)

    hipMemsetAsync(ws, 0, MB, stream);
    zero_pads<<<32, 256, 0, stream>>>(P0, P1);
    wconv<<<dim3(32, 32, 3), dim3(32, 8), 0, stream>>>(conv1_w, WT);
    wconv<<<dim3(32, 32, 3), dim3(32, 8), 0, stream>>>(conv2_w, WT + 3u * (1u << 20));
    wconv<<<dim3(32, 32, 1), dim3(32, 8), 0, stream>>>(proj_w, WT + 6u * (1u << 20));
    wconv<<<dim3(32, 32, 1), dim3(32, 8), 0, stream>>>(ph_w, WT + 7u * (1u << 20));
    // h0 (padded bf16)
    emb_kernel<<<R_ROWS, 256, 0, stream>>>(x, tok, pos, P0);
    // h1 = gelu(conv1(h0)) -> P1 padded
    gemm_mfma<<<dim3(8, 128), 256, 0, stream>>>(P0, WT, conv1_b, nullptr, P1, 3, 1, 1, 1);
    // h2 = gelu(conv2(h1)) -> P0 flat
    gemm_mfma<<<dim3(8, 128), 256, 0, stream>>>(P1, WT + 3u * (1u << 20), conv2_b,
                                                nullptr, P0, 3, 1, 1, 0);
    // LN stats + fused LN-transpose -> F32B [B,D,S] f32
    ln_stats<<<R_ROWS, 256, 0, stream>>>(P0, stats);
    transposeLN<<<dim3(32, 64, 8), dim3(32, 8), 0, stream>>>(P0, stats, ln_g, ln_b, F32B);
    // forward FFT (half-spectrum into F32A) + complexity counts
    fft_fwd<<<BD_ROWS, 256, 0, stream>>>(F32B, (float2*)F32A, counts);
    calc_n<<<1, 64, 0, stream>>>(counts, Ndev);
    // masked inverse FFT -> P1 bf16 [B,D,S]
    fft_inv<<<BD_ROWS, 256, 0, stream>>>((const float2*)F32A, Ndev, P1);
    // [B,D,S] -> [B,S,D] bf16 -> P0 flat (x_ifft_raw)
    transpose_bb<<<dim3(64, 32, 8), dim3(32, 8), 0, stream>>>(P1, P0, D_DIM, S_LEN);
    // proj_out = x_ifft_raw @ proj_w + b -> F32A (recon f32) + P1 (bf16)
    gemm_mfma<<<dim3(8, 128), 256, 0, stream>>>(P0, WT + 6u * (1u << 20), proj_b,
                                                F32A, P1, 1, 0, 0, 0);
    // x_ifft = LN(proj_out) -> d_out (f32) + P0 (bf16), + cos/l1 row stats
    ln_loss<<<R_ROWS, 256, 0, stream>>>(F32A, ln_g, ln_b, out, P0, rowA, rowL1);
    // fused ph stats: px = x_ifft@ph, pt = proj_out@ph -> Sxx/Stt/Sxt
    phstats_mfma<<<dim3(8, 128), 256, 0, stream>>>(P0, P1, WT + 7u * (1u << 20), ph_b,
                                                   Sxx, Stt, Sxt);
    final_loss<<<1, 1024, 0, stream>>>(rowA, rowL1, Sxx, Stt, Sxt, Ndev, out);
}

// Round 5
// 643.998 us; speedup vs baseline: 6.5027x; 1.1528x over previous
//
#include <hip/hip_runtime.h>
#include <math.h>

#define S_LEN 2048
#define D_DIM 1024
#define B_BATCH 8
#define R_ROWS (B_BATCH * S_LEN)    // 16384
#define BD_ROWS (B_BATCH * D_DIM)   // 8192
#define PAD_ROWS 2050               // 1 zero row + 2048 + 1 zero row per batch

typedef unsigned short u16;
typedef unsigned int u32;
typedef __attribute__((ext_vector_type(8))) short bf16x8;
typedef __attribute__((ext_vector_type(4))) float f32x4;

__device__ __forceinline__ u16 f2bf(float f) {
    u32 x = __float_as_uint(f);
    u32 r = (x + 0x7fffu + ((x >> 16) & 1u)) >> 16;   // RNE
    return (u16)r;
}
__device__ __forceinline__ float bf2f(u16 u) {
    return __uint_as_float(((u32)u) << 16);
}
__device__ __forceinline__ float gelu_exact(float x) {
    return 0.5f * x * (1.0f + erff(x * 0.70710678118654752f));
}
// base-4 digit reverse of a 10-bit index
__device__ __forceinline__ int dr4(int v) {
    v = __brev((unsigned)v) >> 22;
    return ((v & 0x155) << 1) | ((v >> 1) & 0x155);
}
#define PIDX(i) ((i) + ((i) >> 5))   // LDS pad: +1 float per 32

#define GLDS(gsrc, ldst)                                                                   \
    __builtin_amdgcn_global_load_lds(                                                      \
        (const __attribute__((address_space(1))) u32*)(gsrc),                              \
        (__attribute__((address_space(3))) u32*)(ldst), 16, 0, 0)

// ----------------------------------------------------------- zero pad rows
__global__ __launch_bounds__(256) void zero_pads(u16* __restrict__ P0, u16* __restrict__ P1)
{
    const int bid = blockIdx.x;          // 0..31
    u16* P = (bid >= 16) ? P1 : P0;
    const int ridx = bid & 15;
    const int b = ridx >> 1;
    const size_t row = (size_t)b * PAD_ROWS + (size_t)(ridx & 1) * (PAD_ROWS - 1);
    ((uint2*)(P + row * D_DIM))[threadIdx.x] = make_uint2(0u, 0u);
}

// ----------------------------------------- weight convert+transpose to bf16
// in: W f32 [T][K][N]; out: WT bf16 [T][N][K]
__global__ __launch_bounds__(256) void wconv(const float* __restrict__ W, u16* __restrict__ WT)
{
    __shared__ float t[32][33];
    const int tap = blockIdx.z;
    const int n0 = blockIdx.x * 32, k0 = blockIdx.y * 32;
    const int tx = threadIdx.x, ty = threadIdx.y;
    const float* ip = W + (size_t)tap * D_DIM * D_DIM;
    u16* op = WT + (size_t)tap * D_DIM * D_DIM;
#pragma unroll
    for (int u = 0; u < 4; u++)
        t[ty + u * 8][tx] = ip[(size_t)(k0 + ty + u * 8) * D_DIM + n0 + tx];
    __syncthreads();
#pragma unroll
    for (int u = 0; u < 4; u++)
        op[(size_t)(n0 + ty + u * 8) * D_DIM + k0 + tx] = f2bf(t[tx][ty + u * 8]);
}

// ------------------- same, but scales row k by g[k]: WT2[n][k] = W[k][n]*g[k]
__global__ __launch_bounds__(256) void wconv_scale(
    const float* __restrict__ W, const float* __restrict__ g, u16* __restrict__ WT2)
{
    __shared__ float t[32][33];
    const int n0 = blockIdx.x * 32, k0 = blockIdx.y * 32;
    const int tx = threadIdx.x, ty = threadIdx.y;
#pragma unroll
    for (int u = 0; u < 4; u++)
        t[ty + u * 8][tx] = W[(size_t)(k0 + ty + u * 8) * D_DIM + n0 + tx];
    __syncthreads();
    const float gk = g[k0 + tx];
#pragma unroll
    for (int u = 0; u < 4; u++)
        WT2[(size_t)(n0 + ty + u * 8) * D_DIM + k0 + tx] = f2bf(t[tx][ty + u * 8] * gk);
}

// -------- vg[n] = sum_k g[k]*WTph[n][k]; c0[n] = sum_k lnb[k]*WTph[n][k]+phb[n]
__global__ __launch_bounds__(256) void gemv_ph(
    const u16* __restrict__ WTph, const float* __restrict__ g,
    const float* __restrict__ lnb, const float* __restrict__ phb,
    float* __restrict__ vg, float* __restrict__ c0)
{
    const int wid = threadIdx.x >> 6, lane = threadIdx.x & 63;
    const int n = blockIdx.x * 4 + wid;   // grid 256
    const u16* wrow = WTph + ((size_t)n << 10) + lane * 16;
    float sg = 0.f, sb = 0.f;
#pragma unroll
    for (int h = 0; h < 2; h++) {
        uint4 w = *(const uint4*)(wrow + h * 8);
        float wv[8];
        wv[0] = bf2f((u16)(w.x & 0xffff)); wv[1] = bf2f((u16)(w.x >> 16));
        wv[2] = bf2f((u16)(w.y & 0xffff)); wv[3] = bf2f((u16)(w.y >> 16));
        wv[4] = bf2f((u16)(w.z & 0xffff)); wv[5] = bf2f((u16)(w.z >> 16));
        wv[6] = bf2f((u16)(w.w & 0xffff)); wv[7] = bf2f((u16)(w.w >> 16));
        const int kb = lane * 16 + h * 8;
        float4 g0 = *(const float4*)(g + kb), g1 = *(const float4*)(g + kb + 4);
        float4 b0 = *(const float4*)(lnb + kb), b1 = *(const float4*)(lnb + kb + 4);
        sg += wv[0]*g0.x + wv[1]*g0.y + wv[2]*g0.z + wv[3]*g0.w
            + wv[4]*g1.x + wv[5]*g1.y + wv[6]*g1.z + wv[7]*g1.w;
        sb += wv[0]*b0.x + wv[1]*b0.y + wv[2]*b0.z + wv[3]*b0.w
            + wv[4]*b1.x + wv[5]*b1.y + wv[6]*b1.z + wv[7]*b1.w;
    }
#pragma unroll
    for (int off = 32; off > 0; off >>= 1) {
        sg += __shfl_xor(sg, off);
        sb += __shfl_xor(sb, off);
    }
    if (lane == 0) { vg[n] = sg; c0[n] = sb + phb[n]; }
}

// ---------------------------------------------------------------- embedding
__global__ __launch_bounds__(256) void emb_kernel(
    const int* __restrict__ x, const float* __restrict__ tok,
    const float* __restrict__ pos, u16* __restrict__ P0)
{
    const int row = blockIdx.x;          // b*S + s
    const int tid = threadIdx.x;
    const int t = x[row];
    const int s = row & (S_LEN - 1);
    const int b = row >> 11;
    float4 a = ((const float4*)(tok + (size_t)t * D_DIM))[tid];
    float4 p = ((const float4*)(pos + (size_t)s * D_DIM))[tid];
    uint2 v;
    v.x = (u32)f2bf(a.x + p.x) | ((u32)f2bf(a.y + p.y) << 16);
    v.y = (u32)f2bf(a.z + p.z) | ((u32)f2bf(a.w + p.w) << 16);
    ((uint2*)(P0 + ((size_t)b * PAD_ROWS + 1 + s) * D_DIM))[tid] = v;
}

// XCD-locality swizzle for grid (8 cols x 128 rows)
__device__ __forceinline__ void swz_blocks(int& bx, int& by) {
    const int flat = blockIdx.y * 8 + blockIdx.x;
    const int xcd = flat & 7;
    const int i = flat >> 3;            // 0..127
    by = xcd * 16 + (i >> 3);
    bx = i & 7;
}

// ------------------------------------------------------- bf16 MFMA GEMM/conv
__global__ __launch_bounds__(256, 2) void gemm_mfma(
    const u16* __restrict__ A, const u16* __restrict__ WT,
    const float* __restrict__ bias,
    float* __restrict__ outF, u16* __restrict__ outB,
    int ntaps, int doGelu, int aPadded, int outBPadded)
{
    __shared__ u16 Abuf[128 * 32];
    __shared__ u16 Bbuf[128 * 32];
    const int tid = threadIdx.x;
    const int wid = tid >> 6, lane = tid & 63;
    const int wr = wid >> 1, wc = wid & 1;
    int bx, by;
    swz_blocks(bx, by);
    const int col0 = bx * 128;
    const int row0 = by * 128;
    const int b = row0 >> 11;
    const int srow0 = row0 & (S_LEN - 1);
    const int l15 = lane & 15, l4 = lane >> 4;

    f32x4 acc[4][4];
#pragma unroll
    for (int i = 0; i < 4; i++)
#pragma unroll
        for (int j = 0; j < 4; j++) acc[i][j] = (f32x4){0.f, 0.f, 0.f, 0.f};

    for (int tap = 0; tap < ntaps; ++tap) {
        const size_t aBase = aPadded ? ((size_t)(b * PAD_ROWS + srow0 + tap) << 10)
                                     : ((size_t)row0 << 10);
        const u16* Wt = WT + ((size_t)tap << 20) + ((size_t)col0 << 10);
        for (int k0 = 0; k0 < D_DIM; k0 += 32) {
#pragma unroll
            for (int c = 0; c < 2; c++) {
                const int chunk = wid + c * 4;
                const int off = chunk * 1024 + lane * 16;   // byte offset in 8KB tile
                const int r = off >> 6;
                const int cb = off & 63;
                GLDS(A + aBase + ((size_t)r << 10) + (size_t)(k0 + (cb >> 1)),
                     (char*)Abuf + off);
                GLDS(Wt + ((size_t)r << 10) + (size_t)(k0 + (cb >> 1)),
                     (char*)Bbuf + off);
            }
            __syncthreads();
            bf16x8 af[4], bfr[4];
#pragma unroll
            for (int mi = 0; mi < 4; mi++)
                af[mi] = *(const bf16x8*)&Abuf[(wr * 64 + mi * 16 + l15) * 32 + l4 * 8];
#pragma unroll
            for (int ni = 0; ni < 4; ni++)
                bfr[ni] = *(const bf16x8*)&Bbuf[(wc * 64 + ni * 16 + l15) * 32 + l4 * 8];
#pragma unroll
            for (int mi = 0; mi < 4; mi++)
#pragma unroll
                for (int ni = 0; ni < 4; ni++)
                    acc[mi][ni] = __builtin_amdgcn_mfma_f32_16x16x32_bf16(
                        af[mi], bfr[ni], acc[mi][ni], 0, 0, 0);
            __syncthreads();
        }
    }

    float bv[4];
#pragma unroll
    for (int ni = 0; ni < 4; ni++) bv[ni] = bias[col0 + wc * 64 + ni * 16 + l15];

#pragma unroll
    for (int mi = 0; mi < 4; mi++) {
#pragma unroll
        for (int ni = 0; ni < 4; ni++) {
#pragma unroll
            for (int reg = 0; reg < 4; reg++) {
                const int row = row0 + wr * 64 + mi * 16 + l4 * 4 + reg;
                const int col = col0 + wc * 64 + ni * 16 + l15;
                float v = acc[mi][ni][reg] + bv[ni];
                if (doGelu) v = gelu_exact(v);
                if (outF) outF[(size_t)row * D_DIM + col] = v;
                if (outB) {
                    const size_t orow = outBPadded
                        ? ((size_t)(row >> 11) * PAD_ROWS + 1 + (size_t)(row & (S_LEN - 1)))
                        : (size_t)row;
                    outB[orow * D_DIM + col] = f2bf(v);
                }
            }
        }
    }
}

// ----- fused ph stats via shared-A: pt = r@W+b; px = rs*(r@W2) - m*rs*vg + c0
// tile 128 rows x 64 cols; waves 2x2 (wave: 64x32)
__global__ __launch_bounds__(256, 3) void phstats_mfma(
    const u16* __restrict__ R, const u16* __restrict__ WT1, const u16* __restrict__ WT2,
    const float* __restrict__ phb, const float* __restrict__ vg, const float* __restrict__ c0,
    const float2* __restrict__ stats2,
    float* __restrict__ Sxx, float* __restrict__ Stt, float* __restrict__ Sxt)
{
    __shared__ u16 Abuf[128 * 32];
    __shared__ u16 B1buf[64 * 32];
    __shared__ u16 B2buf[64 * 32];
    const int tid = threadIdx.x;
    const int wid = tid >> 6, lane = tid & 63;
    const int wr = wid >> 1, wc = wid & 1;
    const int flat = blockIdx.y * 16 + blockIdx.x;   // grid (16,128)
    const int xcd = flat & 7;
    const int i = flat >> 3;            // 0..255
    const int by = xcd * 16 + (i >> 4);
    const int bx = i & 15;
    const int col0 = bx * 64;
    const int row0 = by * 128;
    const int l15 = lane & 15, l4 = lane >> 4;

    f32x4 acc1[4][2], acc2[4][2];
#pragma unroll
    for (int m = 0; m < 4; m++)
#pragma unroll
        for (int n = 0; n < 2; n++) {
            acc1[m][n] = (f32x4){0.f, 0.f, 0.f, 0.f};
            acc2[m][n] = (f32x4){0.f, 0.f, 0.f, 0.f};
        }

    for (int k0 = 0; k0 < D_DIM; k0 += 32) {
#pragma unroll
        for (int c = 0; c < 2; c++) {
            const int off = (wid + c * 4) * 1024 + lane * 16;
            const int r = off >> 6;
            const int cb = off & 63;
            GLDS(R + ((size_t)(row0 + r) << 10) + (size_t)(k0 + (cb >> 1)),
                 (char*)Abuf + off);
        }
        {
            const int off = wid * 1024 + lane * 16;   // 4KB tile
            const int r = off >> 6;                   // 0..63
            const int cb = off & 63;
            GLDS(WT1 + ((size_t)(col0 + r) << 10) + (size_t)(k0 + (cb >> 1)),
                 (char*)B1buf + off);
            GLDS(WT2 + ((size_t)(col0 + r) << 10) + (size_t)(k0 + (cb >> 1)),
                 (char*)B2buf + off);
        }
        __syncthreads();
        bf16x8 af[4], b1f[2], b2f[2];
#pragma unroll
        for (int mi = 0; mi < 4; mi++)
            af[mi] = *(const bf16x8*)&Abuf[(wr * 64 + mi * 16 + l15) * 32 + l4 * 8];
#pragma unroll
        for (int ni = 0; ni < 2; ni++) {
            b1f[ni] = *(const bf16x8*)&B1buf[(wc * 32 + ni * 16 + l15) * 32 + l4 * 8];
            b2f[ni] = *(const bf16x8*)&B2buf[(wc * 32 + ni * 16 + l15) * 32 + l4 * 8];
        }
#pragma unroll
        for (int mi = 0; mi < 4; mi++)
#pragma unroll
            for (int ni = 0; ni < 2; ni++) {
                acc1[mi][ni] = __builtin_amdgcn_mfma_f32_16x16x32_bf16(
                    af[mi], b1f[ni], acc1[mi][ni], 0, 0, 0);
                acc2[mi][ni] = __builtin_amdgcn_mfma_f32_16x16x32_bf16(
                    af[mi], b2f[ni], acc2[mi][ni], 0, 0, 0);
            }
        __syncthreads();
    }

    float phv[2], vgv[2], c0v[2];
#pragma unroll
    for (int ni = 0; ni < 2; ni++) {
        const int col = col0 + wc * 32 + ni * 16 + l15;
        phv[ni] = phb[col]; vgv[ni] = vg[col]; c0v[ni] = c0[col];
    }
#pragma unroll
    for (int mi = 0; mi < 4; mi++) {
#pragma unroll
        for (int reg = 0; reg < 4; reg++) {
            const int row = row0 + wr * 64 + mi * 16 + l4 * 4 + reg;
            const float2 st = stats2[row];           // (m, rs)
            const float mrs = st.x * st.y;
            float sxx = 0.f, stt = 0.f, sxt = 0.f;
#pragma unroll
            for (int ni = 0; ni < 2; ni++) {
                float pt = acc1[mi][ni][reg] + phv[ni];
                float px = st.y * acc2[mi][ni][reg] - mrs * vgv[ni] + c0v[ni];
                sxx = fmaf(px, px, sxx);
                stt = fmaf(pt, pt, stt);
                sxt = fmaf(px, pt, sxt);
            }
#pragma unroll
            for (int off = 1; off < 16; off <<= 1) {
                sxx += __shfl_xor(sxx, off);
                stt += __shfl_xor(stt, off);
                sxt += __shfl_xor(sxt, off);
            }
            if (l15 == 0) {
                atomicAdd(&Sxx[row], sxx);
                atomicAdd(&Stt[row], stt);
                atomicAdd(&Sxt[row], sxt);
            }
        }
    }
}

// ------------------------------------------- per-row LN stats (mean, rstd)
__global__ __launch_bounds__(256) void ln_stats(
    const u16* __restrict__ in, float2* __restrict__ stats)
{
    const int row = blockIdx.x;
    const int tid = threadIdx.x;
    uint2 raw = ((const uint2*)(in + (size_t)row * D_DIM))[tid];
    float v0 = bf2f((u16)(raw.x & 0xffff)), v1 = bf2f((u16)(raw.x >> 16));
    float v2 = bf2f((u16)(raw.y & 0xffff)), v3 = bf2f((u16)(raw.y >> 16));
    float s = v0 + v1 + v2 + v3;
    float s2 = v0 * v0 + v1 * v1 + v2 * v2 + v3 * v3;
#pragma unroll
    for (int off = 32; off > 0; off >>= 1) {
        s += __shfl_xor(s, off);
        s2 += __shfl_xor(s2, off);
    }
    __shared__ float red[8];
    if ((tid & 63) == 0) { red[(tid >> 6) * 2] = s; red[(tid >> 6) * 2 + 1] = s2; }
    __syncthreads();
    if (tid == 0) {
        s = red[0] + red[2] + red[4] + red[6];
        s2 = red[1] + red[3] + red[5] + red[7];
        const float m = s * (1.0f / D_DIM);
        const float var = s2 * (1.0f / D_DIM) - m * m;
        stats[row] = make_float2(m, rsqrtf(var + 1e-5f));
    }
}

// ------------------- fused LN + transpose: bf16 [B,S,D] -> f32 [B,D,S]
__global__ __launch_bounds__(256) void transposeLN(
    const u16* __restrict__ in, const float2* __restrict__ stats,
    const float* __restrict__ g, const float* __restrict__ beta,
    float* __restrict__ out)
{
    __shared__ float t[32][33];
    const int b = blockIdx.z;
    const int n0 = blockIdx.x * 32, m0 = blockIdx.y * 32;   // n=d, m=s
    const int tx = threadIdx.x, ty = threadIdx.y;
    const u16* ip = in + (size_t)b * S_LEN * D_DIM;
    float* op = out + (size_t)b * S_LEN * D_DIM;
#pragma unroll
    for (int u = 0; u < 4; u++)
        t[ty + u * 8][tx] = bf2f(ip[(size_t)(m0 + ty + u * 8) * D_DIM + n0 + tx]);
    __syncthreads();
    const float2 st = stats[b * S_LEN + m0 + tx];
#pragma unroll
    for (int u = 0; u < 4; u++) {
        const int d = n0 + ty + u * 8;
        const float val = (t[tx][ty + u * 8] - st.x) * st.y * g[d] + beta[d];
        op[(size_t)d * S_LEN + m0 + tx] = val;
    }
}

// --------------------- forward real-FFT: 2048-pt via 1024-pt radix-4 packing
__global__ __launch_bounds__(256) void fft_fwd(
    const float* __restrict__ in, float2* __restrict__ X, int* __restrict__ counts)
{
    __shared__ float re[1056], im[1056], twr[1024], twi[1024];
    __shared__ float redf[4];
    __shared__ int redi[4];
    const int tid = threadIdx.x;
    const int row = blockIdx.x;          // b*D + d
    const float2* src = (const float2*)(in + (size_t)row * S_LEN);
#pragma unroll
    for (int u = 0; u < 4; u++) {
        int e = tid + u * 256;
        float ang = -3.14159265358979f * (float)e * (1.0f / 512.0f);
        float sn, cs; __sincosf(ang, &sn, &cs);
        twr[e] = cs; twi[e] = sn;
    }
#pragma unroll
    for (int u = 0; u < 4; u++) {
        int t = tid + u * 256;
        float2 z = src[t];               // z[t] = x[2t] + i x[2t+1]
        int p = PIDX(dr4(t));
        re[p] = z.x; im[p] = z.y;
    }
    __syncthreads();
#pragma unroll
    for (int s = 1; s <= 5; ++s) {
        const int mq = 1 << (2 * (s - 1));
        const int fsh = 2 * (5 - s);
        const int j = tid & (mq - 1);
        const int g = tid >> (2 * (s - 1));
        const int i0 = (g << (2 * s)) + j;
        const int e1 = j << fsh;
        const int p0 = PIDX(i0), p1 = PIDX(i0 + mq), p2 = PIDX(i0 + 2 * mq), p3 = PIDX(i0 + 3 * mq);
        float a0r = re[p0], a0i = im[p0];
        float a1r = re[p1], a1i = im[p1];
        float a2r = re[p2], a2i = im[p2];
        float a3r = re[p3], a3i = im[p3];
        float w1r = twr[e1], w1i = twi[e1];
        float w2r = twr[2 * e1], w2i = twi[2 * e1];
        float w3r = twr[3 * e1], w3i = twi[3 * e1];
        float b1r = a1r * w1r - a1i * w1i, b1i = a1r * w1i + a1i * w1r;
        float b2r = a2r * w2r - a2i * w2i, b2i = a2r * w2i + a2i * w2r;
        float b3r = a3r * w3r - a3i * w3i, b3i = a3r * w3i + a3i * w3r;
        float t0r = a0r + b2r, t0i = a0i + b2i;
        float t1r = a0r - b2r, t1i = a0i - b2i;
        float t2r = b1r + b3r, t2i = b1i + b3i;
        float t3r = b1r - b3r, t3i = b1i - b3i;
        re[p0] = t0r + t2r; im[p0] = t0i + t2i;
        re[p2] = t0r - t2r; im[p2] = t0i - t2i;
        re[p1] = t1r + t3i; im[p1] = t1i - t3r;   // t1 - i*t3
        re[p3] = t1r - t3i; im[p3] = t1i + t3r;   // t1 + i*t3
        __syncthreads();
    }
    // post-process: X[k] = E[k] + w2^k O[k], k<1024
    float2* dst = X + (size_t)row * 1024;
    float mag[4];
    float xtra = 0.0f;
    float lmax = 0.0f;
#pragma unroll
    for (int u = 0; u < 4; u++) {
        int k = tid + u * 256;
        int mk = (1024 - k) & 1023;
        float rk = re[PIDX(k)], ik = im[PIDX(k)];
        float rm = re[PIDX(mk)], imm = im[PIDX(mk)];
        float er = 0.5f * (rk + rm);
        float ei = 0.5f * (ik - imm);
        float orr = 0.5f * (ik + imm);
        float oii = -0.5f * (rk - rm);
        float ang = -3.14159265358979f * (float)k * (1.0f / 1024.0f);
        float sn, cs; __sincosf(ang, &sn, &cs);
        float xr = er + orr * cs - oii * sn;
        float xi = ei + orr * sn + oii * cs;
        dst[k] = make_float2(xr, xi);
        float m2 = xr * xr + xi * xi;
        mag[u] = m2;
        lmax = fmaxf(lmax, m2);
        if (k == 0) {
            float x1024 = re[PIDX(0)] - im[PIDX(0)];
            xtra = x1024 * x1024;
            lmax = fmaxf(lmax, xtra);
        }
    }
#pragma unroll
    for (int off = 32; off > 0; off >>= 1) lmax = fmaxf(lmax, __shfl_xor(lmax, off));
    if ((tid & 63) == 0) redf[tid >> 6] = lmax;
    __syncthreads();
    const float bmax = fmaxf(fmaxf(redf[0], redf[1]), fmaxf(redf[2], redf[3]));
    const float thr = 0.01f * bmax;
    int lc = 0;
#pragma unroll
    for (int u = 0; u < 4; u++) {
        int k = tid + u * 256;
        lc += (mag[u] > thr) ? ((k == 0) ? 1 : 2) : 0;
    }
    if (tid == 0) lc += (xtra > thr) ? 1 : 0;
#pragma unroll
    for (int off = 32; off > 0; off >>= 1) lc += __shfl_xor(lc, off);
    if ((tid & 63) == 0) redi[tid >> 6] = lc;
    __syncthreads();
    if (tid == 0)
        atomicAdd(&counts[(row >> 10) * 64 + (row & 63)],
                  redi[0] + redi[1] + redi[2] + redi[3]);
}

// ------------------------------------------------------------- N from counts
__global__ void calc_n(const int* __restrict__ counts, int* __restrict__ Ndev)
{
    const int t = threadIdx.x;           // 64 threads
    for (int b = 0; b < B_BATCH; b++) {
        int c = counts[b * 64 + t];
#pragma unroll
        for (int off = 32; off > 0; off >>= 1) c += __shfl_xor(c, off);
        if (t == 0) {
            float cf = (float)c * (1.0f / 2097152.0f);
            float cr = 0.5f * (1.0f - cf);
            cr = fminf(fmaxf(cr, 0.1f), 1.0f);
            int n = (int)(cr * 2048.0f);
            n = n < 1 ? 1 : (n > S_LEN ? S_LEN : n);
            Ndev[b] = n;
        }
    }
}

// --------------------- masked inverse 2048-ifft (real part) -> bf16 [B,D,S]
__global__ __launch_bounds__(256) void fft_inv(
    const float2* __restrict__ X, const int* __restrict__ Ndev,
    u16* __restrict__ outb)
{
    __shared__ float re[1056], im[1056], twr[1024], twi[1024];
    const int tid = threadIdx.x;
    const int row = blockIdx.x;          // b*D + d
    const int Nb = Ndev[row >> 10];
    const float2* src = X + (size_t)row * 1024;
#pragma unroll
    for (int u = 0; u < 4; u++) {
        int e = tid + u * 256;
        float ang = 3.14159265358979f * (float)e * (1.0f / 512.0f);
        float sn, cs; __sincosf(ang, &sn, &cs);
        twr[e] = cs; twi[e] = sn;
    }
#pragma unroll
    for (int u = 0; u < 4; u++) {
        int k = tid + u * 256;
        float Ar = 0.f, Ai = 0.f, Br = 0.f, Bi = 0.f;
        if (k == 0) {
            float2 h = src[0];
            Ar = h.x; Ai = h.y;
        } else {
            if (k < Nb) { float2 h = src[k]; Ar = 0.5f * h.x; Ai = 0.5f * h.y; }
            int km = 1024 - k;
            if (km < Nb) { float2 h = src[km]; Br = 0.5f * h.x; Bi = -0.5f * h.y; }
        }
        float ang = 3.14159265358979f * (float)k * (1.0f / 1024.0f);
        float sn, cs; __sincosf(ang, &sn, &cs);
        float drr = Ar - Br, dri = Ai - Bi;
        float Dr = drr * cs - dri * sn;
        float Di = drr * sn + dri * cs;
        float Cr = (Ar + Br) - Di;
        float Ci = (Ai + Bi) + Dr;
        int p = PIDX(dr4(k));
        re[p] = Cr; im[p] = Ci;
    }
    __syncthreads();
#pragma unroll
    for (int s = 1; s <= 4; ++s) {
        const int mq = 1 << (2 * (s - 1));
        const int fsh = 2 * (5 - s);
        const int j = tid & (mq - 1);
        const int g = tid >> (2 * (s - 1));
        const int i0 = (g << (2 * s)) + j;
        const int e1 = j << fsh;
        const int p0 = PIDX(i0), p1 = PIDX(i0 + mq), p2 = PIDX(i0 + 2 * mq), p3 = PIDX(i0 + 3 * mq);
        float a0r = re[p0], a0i = im[p0];
        float a1r = re[p1], a1i = im[p1];
        float a2r = re[p2], a2i = im[p2];
        float a3r = re[p3], a3i = im[p3];
        float w1r = twr[e1], w1i = twi[e1];
        float w2r = twr[2 * e1], w2i = twi[2 * e1];
        float w3r = twr[3 * e1], w3i = twi[3 * e1];
        float b1r = a1r * w1r - a1i * w1i, b1i = a1r * w1i + a1i * w1r;
        float b2r = a2r * w2r - a2i * w2i, b2i = a2r * w2i + a2i * w2r;
        float b3r = a3r * w3r - a3i * w3i, b3i = a3r * w3i + a3i * w3r;
        float t0r = a0r + b2r, t0i = a0i + b2i;
        float t1r = a0r - b2r, t1i = a0i - b2i;
        float t2r = b1r + b3r, t2i = b1i + b3i;
        float t3r = b1r - b3r, t3i = b1i - b3i;
        re[p0] = t0r + t2r; im[p0] = t0i + t2i;
        re[p2] = t0r - t2r; im[p2] = t0i - t2i;
        re[p1] = t1r - t3i; im[p1] = t1i + t3r;   // t1 + i*t3
        re[p3] = t1r + t3i; im[p3] = t1i - t3r;   // t1 - i*t3
        __syncthreads();
    }
    // stage 5: registers -> global (packed bf16)
    {
        const int j = tid;               // mq = 256
        const int e1 = j;
        const int p0 = PIDX(j), p1 = PIDX(j + 256), p2 = PIDX(j + 512), p3 = PIDX(j + 768);
        float a0r = re[p0], a0i = im[p0];
        float a1r = re[p1], a1i = im[p1];
        float a2r = re[p2], a2i = im[p2];
        float a3r = re[p3], a3i = im[p3];
        float w1r = twr[e1], w1i = twi[e1];
        float w2r = twr[2 * e1], w2i = twi[2 * e1];
        float w3r = twr[3 * e1], w3i = twi[3 * e1];
        float b1r = a1r * w1r - a1i * w1i, b1i = a1r * w1i + a1i * w1r;
        float b2r = a2r * w2r - a2i * w2i, b2i = a2r * w2i + a2i * w2r;
        float b3r = a3r * w3r - a3i * w3i, b3i = a3r * w3i + a3i * w3r;
        float t0r = a0r + b2r, t0i = a0i + b2i;
        float t1r = a0r - b2r, t1i = a0i - b2i;
        float t2r = b1r + b3r, t2i = b1i + b3i;
        float t3r = b1r - b3r, t3i = b1i - b3i;
        const float sc = 1.0f / 2048.0f;
        u32* dst = (u32*)(outb + (size_t)row * S_LEN);
        dst[j]       = (u32)f2bf((t0r + t2r) * sc) | ((u32)f2bf((t0i + t2i) * sc) << 16);
        dst[j + 256] = (u32)f2bf((t1r - t3i) * sc) | ((u32)f2bf((t1i + t3r) * sc) << 16);
        dst[j + 512] = (u32)f2bf((t0r - t2r) * sc) | ((u32)f2bf((t0i - t2i) * sc) << 16);
        dst[j + 768] = (u32)f2bf((t1r + t3i) * sc) | ((u32)f2bf((t1i - t3r) * sc) << 16);
    }
}

// ---------------------- bf16 transpose [B][M][N] -> [B][N][M]
__global__ __launch_bounds__(256) void transpose_bb(
    const u16* __restrict__ in, u16* __restrict__ out, int M, int N)
{
    __shared__ u16 t[32][33];
    const int b = blockIdx.z;
    const int n0 = blockIdx.x * 32, m0 = blockIdx.y * 32;
    const int tx = threadIdx.x, ty = threadIdx.y;
    const u16* ip = in + (size_t)b * M * N;
    u16* op = out + (size_t)b * M * N;
#pragma unroll
    for (int u = 0; u < 4; u++)
        t[ty + u * 8][tx] = ip[(size_t)(m0 + ty + u * 8) * N + n0 + tx];
    __syncthreads();
#pragma unroll
    for (int u = 0; u < 4; u++)
        op[(size_t)(n0 + ty + u * 8) * M + m0 + tx] = t[tx][ty + u * 8];
}

// ----------- LN(proj_out) + cos-sim/smooth-L1 row stats; exports (m,rs)
__global__ __launch_bounds__(256) void ln_loss(
    const float* __restrict__ in, const float* __restrict__ g,
    const float* __restrict__ beta, float* __restrict__ outF,
    float2* __restrict__ stats2,
    float* __restrict__ rowA, float* __restrict__ rowL1)
{
    const int row = blockIdx.x;
    const int tid = threadIdx.x;
    float4 v = ((const float4*)(in + (size_t)row * D_DIM))[tid];
    float s = v.x + v.y + v.z + v.w;
    float s2 = v.x * v.x + v.y * v.y + v.z * v.z + v.w * v.w;
#pragma unroll
    for (int off = 32; off > 0; off >>= 1) {
        s += __shfl_xor(s, off);
        s2 += __shfl_xor(s2, off);
    }
    __shared__ float red[8];
    if ((tid & 63) == 0) { red[(tid >> 6) * 2] = s; red[(tid >> 6) * 2 + 1] = s2; }
    __syncthreads();
    s = red[0] + red[2] + red[4] + red[6];
    s2 = red[1] + red[3] + red[5] + red[7];
    const float m = s * (1.0f / D_DIM);
    const float var = s2 * (1.0f / D_DIM) - m * m;
    const float rs = rsqrtf(var + 1e-5f);
    float4 gg = ((const float4*)g)[tid];
    float4 bb = ((const float4*)beta)[tid];
    float4 o;
    o.x = (v.x - m) * rs * gg.x + bb.x;
    o.y = (v.y - m) * rs * gg.y + bb.y;
    o.z = (v.z - m) * rs * gg.z + bb.z;
    o.w = (v.w - m) * rs * gg.w + bb.w;
    ((float4*)(outF + (size_t)row * D_DIM))[tid] = o;

    float xx = o.x * o.x + o.y * o.y + o.z * o.z + o.w * o.w;
    float rr = v.x * v.x + v.y * v.y + v.z * v.z + v.w * v.w;
    float xr = o.x * v.x + o.y * v.y + o.z * v.z + o.w * v.w;
    float l1 = 0.f;
    {
        float d, ad;
        d = o.x - v.x; ad = fabsf(d); l1 += (ad < 1.0f) ? 0.5f * d * d : ad - 0.5f;
        d = o.y - v.y; ad = fabsf(d); l1 += (ad < 1.0f) ? 0.5f * d * d : ad - 0.5f;
        d = o.z - v.z; ad = fabsf(d); l1 += (ad < 1.0f) ? 0.5f * d * d : ad - 0.5f;
        d = o.w - v.w; ad = fabsf(d); l1 += (ad < 1.0f) ? 0.5f * d * d : ad - 0.5f;
    }
#pragma unroll
    for (int off = 32; off > 0; off >>= 1) {
        xx += __shfl_xor(xx, off); rr += __shfl_xor(rr, off);
        xr += __shfl_xor(xr, off); l1 += __shfl_xor(l1, off);
    }
    __shared__ float red2[4][4];
    __syncthreads();
    if ((tid & 63) == 0) {
        int w = tid >> 6;
        red2[w][0] = xx; red2[w][1] = rr; red2[w][2] = xr; red2[w][3] = l1;
    }
    __syncthreads();
    if (tid == 0) {
        stats2[row] = make_float2(m, rs);
        xx = red2[0][0] + red2[1][0] + red2[2][0] + red2[3][0];
        rr = red2[0][1] + red2[1][1] + red2[2][1] + red2[3][1];
        xr = red2[0][2] + red2[1][2] + red2[2][2] + red2[3][2];
        l1 = red2[0][3] + red2[1][3] + red2[2][3] + red2[3][3];
        float nx = fmaxf(sqrtf(xx), 1e-12f);
        float nr = fmaxf(sqrtf(rr), 1e-12f);
        float cs = xr / (nx * nr);
        cs = fminf(fmaxf(cs, -1.0f + 1e-8f), 1.0f - 1e-8f);
        rowA[row] = 1.0f - cs;
        rowL1[row] = l1;
    }
}

// ------------------------------------------------------------- final loss
__global__ __launch_bounds__(1024) void final_loss(
    const float* __restrict__ rowA, const float* __restrict__ rowL1,
    const float* __restrict__ Sxx, const float* __restrict__ Stt,
    const float* __restrict__ Sxt,
    const int* __restrict__ Ndev, float* __restrict__ out)
{
    const int tid = threadIdx.x;
    float sa = 0.f, sb = 0.f;
#pragma unroll
    for (int i = 0; i < 16; i++) {
        int r = tid + i * 1024;
        sa += rowA[r];
        int b = r >> 11, s = r & (S_LEN - 1);
        if (s < Ndev[b]) {
            float sx = Sxx[r], st = Stt[r], sxtv = Sxt[r];
            float nxx = fmaxf(sqrtf(sx), 1e-12f);
            float ntt = fmaxf(sqrtf(st), 1e-12f);
            float sem = (sx / (nxx * nxx) + st / (ntt * ntt)
                         - 2.0f * sxtv / (nxx * ntt)) * (1.0f / D_DIM);
            sb += 0.2f * (rowL1[r] * (1.0f / D_DIM)) + 0.2f * sem;
        }
    }
#pragma unroll
    for (int off = 32; off > 0; off >>= 1) {
        sa += __shfl_xor(sa, off);
        sb += __shfl_xor(sb, off);
    }
    __shared__ float ra[16], rb[16];
    if ((tid & 63) == 0) { ra[tid >> 6] = sa; rb[tid >> 6] = sb; }
    __syncthreads();
    if (tid == 0) {
        float A = 0.f, Bs = 0.f;
#pragma unroll
        for (int i = 0; i < 16; i++) { A += ra[i]; Bs += rb[i]; }
        int K = 0;
        for (int b = 0; b < B_BATCH; b++) K += Ndev[b];
        float Kf = (float)K;
        float M = A * (1.0f / 16384.0f);
        out[(size_t)R_ROWS * D_DIM] = (0.6f * M * Kf + Bs) / (Kf + 1e-8f);
    }
}

// ---------------------------------------------------------------------------
extern "C" void kernel_launch(void* const* d_in, const int* in_sizes, int n_in,
                              void* d_out, int out_size, void* d_ws, size_t ws_size,
                              hipStream_t stream)
{
    (void)in_sizes; (void)n_in; (void)out_size; (void)ws_size;
    const int*   x       = (const int*)  d_in[0];
    const float* tok     = (const float*)d_in[1];
    const float* pos     = (const float*)d_in[2];
    const float* conv1_w = (const float*)d_in[3];
    const float* conv1_b = (const float*)d_in[4];
    const float* conv2_w = (const float*)d_in[5];
    const float* conv2_b = (const float*)d_in[6];
    const float* proj_w  = (const float*)d_in[7];
    const float* proj_b  = (const float*)d_in[8];
    const float* ph_w    = (const float*)d_in[9];
    const float* ph_b    = (const float*)d_in[10];
    const float* ln_g    = (const float*)d_in[11];
    const float* ln_b    = (const float*)d_in[12];
    float* out = (float*)d_out;

    char* ws = (char*)d_ws;
    int*    counts = (int*)(ws);                         // 512 ints
    int*    Ndev   = (int*)(ws + 2048);
    float2* stats  = (float2*)(ws + 4096);               // 128 KB
    float2* stats2 = (float2*)(ws + 135168);             // 128 KB
    float*  Sxx    = (float*)(ws + 266240);
    float*  Stt    = (float*)(ws + 331776);
    float*  Sxt    = (float*)(ws + 397312);
    float*  rowA   = (float*)(ws + 462848);
    float*  rowL1  = (float*)(ws + 528384);
    float*  vg     = (float*)(ws + 593920);
    float*  c0     = (float*)(ws + 598016);              // ends 602112 < 1MB
    const size_t MB = 1ull << 20;
    u16*   WT   = (u16*)(ws + 1 * MB);      // 8 slots x 2MB; slot 0 reused for WT2ph
    u16*   WT2  = WT;                       // ph scaled weights (after conv1 done)
    u16*   P0   = (u16*)(ws + 17 * MB);     // 32.03 MB padded bf16 activations
    u16*   P1   = (u16*)(ws + 50 * MB);     // 32.03 MB
    float* F32A = (float*)(ws + 83 * MB);   // 64 MiB (spectrum, then recon f32)
    float* F32B = (float*)(ws + 148 * MB);  // 64 MiB (LN'd [B,D,S] f32)

    hipMemsetAsync(ws, 0, MB, stream);
    zero_pads<<<32, 256, 0, stream>>>(P0, P1);
    wconv<<<dim3(32, 32, 3), dim3(32, 8), 0, stream>>>(conv1_w, WT);
    wconv<<<dim3(32, 32, 3), dim3(32, 8), 0, stream>>>(conv2_w, WT + 3u * (1u << 20));
    wconv<<<dim3(32, 32, 1), dim3(32, 8), 0, stream>>>(proj_w, WT + 6u * (1u << 20));
    wconv<<<dim3(32, 32, 1), dim3(32, 8), 0, stream>>>(ph_w, WT + 7u * (1u << 20));
    gemv_ph<<<256, 256, 0, stream>>>(WT + 7u * (1u << 20), ln_g, ln_b, ph_b, vg, c0);
    // h0 (padded bf16)
    emb_kernel<<<R_ROWS, 256, 0, stream>>>(x, tok, pos, P0);
    // h1 = gelu(conv1(h0)) -> P1 padded
    gemm_mfma<<<dim3(8, 128), 256, 0, stream>>>(P0, WT, conv1_b, nullptr, P1, 3, 1, 1, 1);
    // conv1 weights now dead: WT2ph = diag(g)*ph_w transposed into slot 0
    wconv_scale<<<dim3(32, 32, 1), dim3(32, 8), 0, stream>>>(ph_w, ln_g, WT2);
    // h2 = gelu(conv2(h1)) -> P0 flat
    gemm_mfma<<<dim3(8, 128), 256, 0, stream>>>(P1, WT + 3u * (1u << 20), conv2_b,
                                                nullptr, P0, 3, 1, 1, 0);
    // LN stats + fused LN-transpose -> F32B [B,D,S] f32
    ln_stats<<<R_ROWS, 256, 0, stream>>>(P0, stats);
    transposeLN<<<dim3(32, 64, 8), dim3(32, 8), 0, stream>>>(P0, stats, ln_g, ln_b, F32B);
    // forward FFT (half-spectrum into F32A) + complexity counts
    fft_fwd<<<BD_ROWS, 256, 0, stream>>>(F32B, (float2*)F32A, counts);
    calc_n<<<1, 64, 0, stream>>>(counts, Ndev);
    // masked inverse FFT -> P1 bf16 [B,D,S]
    fft_inv<<<BD_ROWS, 256, 0, stream>>>((const float2*)F32A, Ndev, P1);
    // [B,D,S] -> [B,S,D] bf16 -> P0 flat (x_ifft_raw)
    transpose_bb<<<dim3(64, 32, 8), dim3(32, 8), 0, stream>>>(P1, P0, D_DIM, S_LEN);
    // proj_out = x_ifft_raw @ proj_w + b -> F32A (recon f32) + P1 (bf16 flat)
    gemm_mfma<<<dim3(8, 128), 256, 0, stream>>>(P0, WT + 6u * (1u << 20), proj_b,
                                                F32A, P1, 1, 0, 0, 0);
    // x_ifft = LN(proj_out) -> d_out + stats2 + cos/l1 row stats
    ln_loss<<<R_ROWS, 256, 0, stream>>>(F32A, ln_g, ln_b, out, stats2, rowA, rowL1);
    // fused ph stats from shared A = proj bf16
    phstats_mfma<<<dim3(16, 128), 256, 0, stream>>>(P1, WT + 7u * (1u << 20), WT2,
                                                    ph_b, vg, c0, stats2, Sxx, Stt, Sxt);
    final_loss<<<1, 1024, 0, stream>>>(rowA, rowL1, Sxx, Stt, Sxt, Ndev, out);
}